// Round 4
// baseline (206.965 us; speedup 1.0000x reference)
//
#include <hip/hip_runtime.h>

// ---------------------------------------------------------------------------
// MHABlock: fused cvt -> QKV GEMM (global_load_lds staging) -> fused K/V
// transpose -> split-K flash attention (no-max online softmax; row sums via
// ones-MFMA; packed bf16 cvt; swizzled LDS, 5 blocks/CU) -> deferred
// normalize + residual + LayerNorm.
// ---------------------------------------------------------------------------

typedef __bf16 bf16x8 __attribute__((ext_vector_type(8)));
typedef __bf16 bf16x4 __attribute__((ext_vector_type(4)));
typedef float  f32x4  __attribute__((ext_vector_type(4)));
typedef unsigned short u16x4 __attribute__((ext_vector_type(4)));
typedef short          s16x8 __attribute__((ext_vector_type(8)));

#define N_TOK   4096
#define D_MODEL 640
#define DK      64
#define HSLAB   (N_TOK * DK)
// exp(s/64) = 2^(s * log2(e)/64)
#define EXP2SCL 0.022542110f

__device__ __forceinline__ void stage16(const unsigned short* g, unsigned short* lds_uniform) {
    __builtin_amdgcn_global_load_lds(
        (const __attribute__((address_space(1))) unsigned int*)g,
        (__attribute__((address_space(3))) unsigned int*)lds_uniform, 16, 0, 0);
}

__device__ __forceinline__ u16x4 cvt4(f32x4 v) {
    return __builtin_bit_cast(u16x4, __builtin_convertvector(v, bf16x4));
}

// ------------------- fused fp32 -> bf16 (x then Wq,Wk,Wv) ------------------
__global__ __launch_bounds__(256) void cvt_all(const float* __restrict__ x,
                                               const float* __restrict__ w0,
                                               const float* __restrict__ w1,
                                               const float* __restrict__ w2,
                                               unsigned short* __restrict__ xb,
                                               unsigned short* __restrict__ d0,
                                               unsigned short* __restrict__ d1,
                                               unsigned short* __restrict__ d2) {
    int i = blockIdx.x * 256 + threadIdx.x;   // grid exactly 962560 f4 elems
    const float* s; unsigned short* d; int off;
    if (i < 655360) { s = x; d = xb; off = i; }
    else {
        int j = i - 655360;
        int w = j / 102400; off = j - w * 102400;
        s = (w == 0) ? w0 : (w == 1) ? w1 : w2;
        d = (w == 0) ? d0 : (w == 1) ? d1 : d2;
    }
    f32x4 v = ((const f32x4*)s)[off];
    ((u16x4*)d)[off] = cvt4(v);
}

// ------------------------ QKV NT-GEMM: C = x @ W^T -------------------------
// M=4096, N=640, K=640. 128x128 tile, BK=32, 4 waves each 64x64.
// Staging via global_load_lds w=16 with XOR unit swizzle (4 units/row of 8).
__global__ __launch_bounds__(256, 2) void gemm_qkv(
    const unsigned short* __restrict__ xb,
    const unsigned short* __restrict__ wq,
    const unsigned short* __restrict__ wk,
    const unsigned short* __restrict__ wv,
    unsigned short* __restrict__ Qo,
    unsigned short* __restrict__ Ko,
    unsigned short* __restrict__ Vo) {
    const int mode = blockIdx.z;
    const unsigned short* W = (mode == 0) ? wq : (mode == 1) ? wk : wv;
    unsigned short*       C = (mode == 0) ? Qo : (mode == 1) ? Ko : Vo;
    const int m0 = blockIdx.y * 128;
    const int n0 = blockIdx.x * 128;

    __shared__ unsigned short As[4096];   // 128 rows x 32, chunk-swizzled
    __shared__ unsigned short Bs[4096];

    const int tid  = threadIdx.x;
    const int lane = tid & 63;
    const int wave = tid >> 6;
    const int quad = lane >> 4, l16 = lane & 15;
    const int wm = (wave >> 1) * 64, wn = (wave & 1) * 64;
    const int swz3 = l16 & 3;

    f32x4 acc[4][4] = {};

    // chunk c = j*256 + wave*64 + lane; row = c>>2, unit = (c&3)^(row&3)
    const int c0 = wave * 64 + lane, c1 = c0 + 256;
    const int r0 = c0 >> 2, u0 = ((c0 & 3) ^ (r0 & 3)) * 8;
    const int r1 = c1 >> 2, u1 = ((c1 & 3) ^ (r1 & 3)) * 8;
    const int lb0 = (wave * 64) * 8, lb1 = lb0 + 2048;   // LDS elem bases

    for (int kt = 0; kt < D_MODEL; kt += 32) {
        __syncthreads();
        stage16(&xb[(size_t)(m0 + r0) * D_MODEL + kt + u0], As + lb0);
        stage16(&xb[(size_t)(m0 + r1) * D_MODEL + kt + u1], As + lb1);
        stage16(&W [(size_t)(n0 + r0) * D_MODEL + kt + u0], Bs + lb0);
        stage16(&W [(size_t)(n0 + r1) * D_MODEL + kt + u1], Bs + lb1);
        __syncthreads();

        bf16x8 af[4], bfr[4];
        for (int mi = 0; mi < 4; mi++)
            af[mi] = *(const bf16x8*)&As[(wm + mi * 16 + l16) * 32 + (quad ^ swz3) * 8];
        for (int ni = 0; ni < 4; ni++)
            bfr[ni] = *(const bf16x8*)&Bs[(wn + ni * 16 + l16) * 32 + (quad ^ swz3) * 8];
        for (int mi = 0; mi < 4; mi++)
            for (int ni = 0; ni < 4; ni++)
                acc[mi][ni] = __builtin_amdgcn_mfma_f32_16x16x32_bf16(af[mi], bfr[ni], acc[mi][ni], 0, 0, 0);
    }

    for (int mi = 0; mi < 4; mi++)
        for (int ni = 0; ni < 4; ni++) {
            u16x4 cv = cvt4(acc[mi][ni]);
            for (int r = 0; r < 4; r++) {
                int row = m0 + wm + mi * 16 + quad * 4 + r;
                int col = n0 + wn + ni * 16 + l16;
                C[(size_t)row * D_MODEL + col] = cv[r];
            }
        }
}

// ---------------- fused per-head transpose: K' and V' ----------------------
// z < 10: K head z, [64][4096] -> [4096][64];  z >= 10: V head z-10,
// [4096][64] -> [64][4096]. grid (64, 1, 20).
__global__ __launch_bounds__(256) void transpose_kv(
    const unsigned short* __restrict__ Kn, unsigned short* __restrict__ Kp,
    const unsigned short* __restrict__ Vn, unsigned short* __restrict__ Vp) {
    __shared__ unsigned short T[64][66];
    const int z = blockIdx.z;
    const unsigned short* src; unsigned short* dst;
    int R, Cc, r0, c0;
    if (z < 10) { src = Kn; dst = Kp; R = 64;   Cc = 4096; r0 = 0; c0 = blockIdx.x * 64; }
    else        { src = Vn; dst = Vp; R = 4096; Cc = 64;   r0 = blockIdx.x * 64; c0 = 0; }
    const size_t hb = (size_t)(z % 10) * HSLAB;
    const int t = threadIdx.x;
    const int rr = t >> 3, c8 = (t & 7) * 8;

    for (int hf = 0; hf < 2; hf++) {
        int r = rr + hf * 32;
        bf16x8 v = *(const bf16x8*)&src[hb + (size_t)(r0 + r) * Cc + c0 + c8];
        for (int j = 0; j < 8; j++) T[r][c8 + j] = ((unsigned short*)&v)[j];
    }
    __syncthreads();
    for (int hf = 0; hf < 2; hf++) {
        int oc = rr + hf * 32;
        unsigned short v[8];
        for (int j = 0; j < 8; j++) v[j] = T[c8 + j][oc];
        *(bf16x8*)&dst[hb + (size_t)(c0 + oc) * R + r0 + c8] = *(bf16x8*)v;
    }
}

// ------------------------------- attention ---------------------------------
// grid (320, 4): x = head*32 + qtile(128 rows), y = kpart (1024 keys).
// LDS: Kt 8K + Vt 8K + Pb 16K = 32768 -> exactly 5 blocks/CU.
__global__ __launch_bounds__(256, 5) void attn(
    const unsigned short* __restrict__ Qb,
    const unsigned short* __restrict__ Kp,   // [h][m][k]
    const unsigned short* __restrict__ Vp,   // [h][k][m]
    float* __restrict__ vals,                // pre-zeroed
    float* __restrict__ l_tot) {             // pre-zeroed
    const int h  = blockIdx.x >> 5;
    const int qt = blockIdx.x & 31;
    const int kbase = blockIdx.y << 10;
    const int lane = threadIdx.x & 63;
    const int wave = threadIdx.x >> 6;
    const int quad = lane >> 4, l16 = lane & 15;
    const size_t hoff = (size_t)h * HSLAB;

    __shared__ unsigned short Kt[4096];          // 64x64, unit-swizzled
    __shared__ unsigned short Vt[4096];
    __shared__ unsigned short Pb[4][32 * 64];    // per-wave 32x64, swizzled
    unsigned short* Pw = &Pb[wave][0];

    const int qbase = qt * 128 + wave * 32;
    bf16x8 qf[2][2];
    for (int g = 0; g < 2; g++)
        for (int kh = 0; kh < 2; kh++)
            qf[g][kh] = *(const bf16x8*)&Qb[hoff + (size_t)(qbase + g * 16 + l16) * DK + kh * 32 + quad * 8];

    f32x4 o[2][4] = {};
    f32x4 ol[2] = {};
    const bf16x8 ones = __builtin_bit_cast(bf16x8, (s16x8)(short)0x3F80);

    // staging: 8 instrs of 64 chunks; chunk c: row=c>>3, unit=(c&7)^(row&7)
    const int s0 = wave * 128 + lane;
    const int s1 = s0 + 64;
    const int kr0 = s0 >> 3, kc0 = (s0 & 7) ^ (kr0 & 7);
    const int kr1 = s1 >> 3, kc1 = (s1 & 7) ^ (kr1 & 7);
    const int swz = l16 & 7;

    for (int it = 0; it < 16; it++) {
        const int m0 = kbase + it * 64;
        __syncthreads();
        stage16(Kp + hoff + (size_t)(m0 + kr0) * DK + kc0 * 8, Kt + wave * 1024);
        stage16(Kp + hoff + (size_t)(m0 + kr1) * DK + kc1 * 8, Kt + wave * 1024 + 512);
        stage16(Vp + hoff + (size_t)kr0 * N_TOK + m0 + kc0 * 8, Vt + wave * 1024);
        stage16(Vp + hoff + (size_t)kr1 * N_TOK + m0 + kc1 * 8, Vt + wave * 1024 + 512);
        __syncthreads();

        // ---- S^T tiles: A = K rows (key), B = Q rows (q) ----
        for (int ni = 0; ni < 4; ni++) {
            const int krow = ni * 16 + l16;
            bf16x8 a0 = *(const bf16x8*)&Kt[krow * 64 + ((0 + quad) ^ swz) * 8];
            bf16x8 a1 = *(const bf16x8*)&Kt[krow * 64 + ((4 + quad) ^ swz) * 8];
            for (int g = 0; g < 2; g++) {
                f32x4 s = {};
                s = __builtin_amdgcn_mfma_f32_16x16x32_bf16(a0, qf[g][0], s, 0, 0, 0);
                s = __builtin_amdgcn_mfma_f32_16x16x32_bf16(a1, qf[g][1], s, 0, 0, 0);
                // lane holds S^T[key=ni*16+quad*4+r][q=g*16+l16]
                f32x4 pv;
                for (int r = 0; r < 4; r++) pv[r] = exp2f(s[r] * EXP2SCL);
                // P[q-row][key], swizzled: unit u8 = ni*2+(quad>>1)
                const int row = g * 16 + l16;
                const int a = row * 64 + ((ni * 2 + (quad >> 1)) ^ swz) * 8 + (quad & 1) * 4;
                *(u16x4*)&Pw[a] = cvt4(pv);
            }
        }

        // ---- P A-fragments (swizzled b128) ----
        bf16x8 pf[2][2];
        for (int g = 0; g < 2; g++)
            for (int mh = 0; mh < 2; mh++)
                pf[g][mh] = *(const bf16x8*)&Pw[(g * 16 + l16) * 64 + ((mh * 4 + quad) ^ swz) * 8];

        // row sums via ones-MFMA (every col of C holds the row sum)
        for (int g = 0; g < 2; g++) {
            ol[g] = __builtin_amdgcn_mfma_f32_16x16x32_bf16(pf[g][0], ones, ol[g], 0, 0, 0);
            ol[g] = __builtin_amdgcn_mfma_f32_16x16x32_bf16(pf[g][1], ones, ol[g], 0, 0, 0);
        }

        // ---- O += P * V ----
        for (int nd = 0; nd < 4; nd++) {
            const int vrow = nd * 16 + l16;
            bf16x8 b0 = *(const bf16x8*)&Vt[vrow * 64 + ((0 + quad) ^ swz) * 8];
            bf16x8 b1 = *(const bf16x8*)&Vt[vrow * 64 + ((4 + quad) ^ swz) * 8];
            for (int g = 0; g < 2; g++) {
                o[g][nd] = __builtin_amdgcn_mfma_f32_16x16x32_bf16(pf[g][0], b0, o[g][nd], 0, 0, 0);
                o[g][nd] = __builtin_amdgcn_mfma_f32_16x16x32_bf16(pf[g][1], b1, o[g][nd], 0, 0, 0);
            }
        }
    }

    // l: C-layout row = quad*4+r, all cols identical -> write from l16==0
    if (l16 == 0)
        for (int g = 0; g < 2; g++)
            for (int r = 0; r < 4; r++)
                atomicAdd(&l_tot[(h << 12) + qbase + g * 16 + quad * 4 + r], ol[g][r]);

    for (int g = 0; g < 2; g++)
        for (int nd = 0; nd < 4; nd++)
            for (int r = 0; r < 4; r++) {
                int q = qbase + g * 16 + quad * 4 + r;
                atomicAdd(&vals[hoff + (size_t)q * DK + nd * 16 + l16], o[g][nd][r]);
            }
}

// ----------------- deferred normalize + residual + LayerNorm ---------------
__global__ __launch_bounds__(256) void ln_kernel(
    const float* __restrict__ vals, const float* __restrict__ l_tot,
    const float* __restrict__ x,
    const float* __restrict__ gamma, const float* __restrict__ beta,
    float* __restrict__ out) {
    const int wave = threadIdx.x >> 6, lane = threadIdx.x & 63;
    const int row  = blockIdx.x * 4 + wave;
    const float* v  = vals + (size_t)row * D_MODEL;
    const float* xr = x    + (size_t)row * D_MODEL;

    float t[10];
    float s = 0.f;
    for (int i = 0; i < 10; i++) {
        float linv = 1.0f / l_tot[row * 10 + i];
        t[i] = v[lane + i * 64] * linv + xr[lane + i * 64];
        s += t[i];
    }
    for (int off = 32; off; off >>= 1) s += __shfl_xor(s, off, 64);
    float mean = s * (1.0f / 640.0f);
    float s2 = 0.f;
    for (int i = 0; i < 10; i++) { float d = t[i] - mean; s2 += d * d; }
    for (int off = 32; off; off >>= 1) s2 += __shfl_xor(s2, off, 64);
    float inv = rsqrtf(s2 * (1.0f / 640.0f) + 1e-5f);

    float* orow = out + (size_t)row * D_MODEL;
    for (int i = 0; i < 10; i++) {
        int c = lane + i * 64;
        orow[c] = (t[i] - mean) * inv * gamma[c] + beta[c];
    }
}

// ------------------------------- launcher ----------------------------------
extern "C" void kernel_launch(void* const* d_in, const int* in_sizes, int n_in,
                              void* d_out, int out_size, void* d_ws, size_t ws_size,
                              hipStream_t stream) {
    const float* x     = (const float*)d_in[0];
    const float* Wq    = (const float*)d_in[1];
    const float* Wk    = (const float*)d_in[2];
    const float* Wv    = (const float*)d_in[3];
    const float* gamma = (const float*)d_in[4];
    const float* beta  = (const float*)d_in[5];
    float* out = (float*)d_out;

    char* ws = (char*)d_ws;
    unsigned short* xb  = (unsigned short*)(ws);               // 5,242,880 B
    unsigned short* wqb = (unsigned short*)(ws + 5242880);
    unsigned short* wkb = (unsigned short*)(ws + 6062080);
    unsigned short* wvb = (unsigned short*)(ws + 6881280);
    unsigned short* Qb  = (unsigned short*)(ws + 7700480);
    unsigned short* Kp  = (unsigned short*)(ws + 12943360);    // K' [h][m][k]
    unsigned short* Vp  = (unsigned short*)(ws + 18186240);    // V' [h][k][m]
    unsigned short* Kn  = (unsigned short*)(ws + 23429120);    // aliases vals
    unsigned short* Vn  = (unsigned short*)(ws + 28672000);
    float*          vals  = (float*)(ws + 23429120);           // 10,485,760 B
    float*          l_tot = (float*)(ws + 33914880);           //   163,840 B

    cvt_all<<<3760, 256, 0, stream>>>(x, Wq, Wk, Wv, xb, wqb, wkb, wvb);

    gemm_qkv<<<dim3(5, 32, 3), 256, 0, stream>>>(xb, wqb, wkb, wvb, Qb, Kn, Vn);

    transpose_kv<<<dim3(64, 1, 20), 256, 0, stream>>>(Kn, Kp, Vn, Vp);

    hipMemsetAsync(vals, 0, 10649600, stream);   // vals + l_tot contiguous

    attn<<<dim3(320, 4), 256, 0, stream>>>(Qb, Kp, Vp, vals, l_tot);
    ln_kernel<<<1024, 256, 0, stream>>>(vals, l_tot, x, gamma, beta, out);
}

// Round 6
// 182.954 us; speedup vs baseline: 1.1312x; 1.1312x over previous
//
#include <hip/hip_runtime.h>

// ---------------------------------------------------------------------------
// MHABlock: fused cvt (+l_tot zero) -> QKV GEMM (global_load_lds staging) ->
// fused K/V transpose (+vals zero-after-read) -> split-K(3, uneven) flash
// attention (no-max online softmax, R3-proven structure, packed bf16 cvt) ->
// deferred normalize + residual + LayerNorm.
// ---------------------------------------------------------------------------

typedef __bf16 bf16x8 __attribute__((ext_vector_type(8)));
typedef __bf16 bf16x4 __attribute__((ext_vector_type(4)));
typedef float  f32x4  __attribute__((ext_vector_type(4)));
typedef unsigned short u16x4 __attribute__((ext_vector_type(4)));

#define N_TOK   4096
#define D_MODEL 640
#define DK      64
#define HSLAB   (N_TOK * DK)
// exp(s/64) = 2^(s * log2(e)/64)
#define EXP2SCL 0.022542110f

__device__ __forceinline__ void stage16(const unsigned short* g, unsigned short* lds_uniform) {
    __builtin_amdgcn_global_load_lds(
        (const __attribute__((address_space(1))) unsigned int*)g,
        (__attribute__((address_space(3))) unsigned int*)lds_uniform, 16, 0, 0);
}

// packed f32x4 -> bf16x4 (compiles to packed cvt on gfx950; RNE verified R4)
__device__ __forceinline__ u16x4 cvt4(f32x4 v) {
    return __builtin_bit_cast(u16x4, __builtin_convertvector(v, bf16x4));
}

// ---------- fused fp32 -> bf16 (x, Wq, Wk, Wv) + l_tot zeroing -------------
// grid 3800: [0,655360) x | [655360,962560) weights | [962560,972800) l_tot=0
__global__ __launch_bounds__(256) void cvt_all(const float* __restrict__ x,
                                               const float* __restrict__ w0,
                                               const float* __restrict__ w1,
                                               const float* __restrict__ w2,
                                               unsigned short* __restrict__ xb,
                                               unsigned short* __restrict__ d0,
                                               unsigned short* __restrict__ d1,
                                               unsigned short* __restrict__ d2,
                                               f32x4* __restrict__ ltot4) {
    int i = blockIdx.x * 256 + threadIdx.x;
    if (i >= 962560) { ltot4[i - 962560] = (f32x4){0.f, 0.f, 0.f, 0.f}; return; }
    const float* s; unsigned short* d; int off;
    if (i < 655360) { s = x; d = xb; off = i; }
    else {
        int j = i - 655360;
        int w = j / 102400; off = j - w * 102400;
        s = (w == 0) ? w0 : (w == 1) ? w1 : w2;
        d = (w == 0) ? d0 : (w == 1) ? d1 : d2;
    }
    f32x4 v = ((const f32x4*)s)[off];
    ((u16x4*)d)[off] = cvt4(v);
}

// ------------------------ QKV NT-GEMM: C = x @ W^T -------------------------
// M=4096, N=640, K=640. 128x128 tile, BK=32, 4 waves each 64x64.
// Staging via global_load_lds w=16 with XOR unit swizzle.
__global__ __launch_bounds__(256, 2) void gemm_qkv(
    const unsigned short* __restrict__ xb,
    const unsigned short* __restrict__ wq,
    const unsigned short* __restrict__ wk,
    const unsigned short* __restrict__ wv,
    unsigned short* __restrict__ Qo,
    unsigned short* __restrict__ Ko,
    unsigned short* __restrict__ Vo) {
    const int mode = blockIdx.z;
    const unsigned short* W = (mode == 0) ? wq : (mode == 1) ? wk : wv;
    unsigned short*       C = (mode == 0) ? Qo : (mode == 1) ? Ko : Vo;
    const int m0 = blockIdx.y * 128;
    const int n0 = blockIdx.x * 128;

    __shared__ unsigned short As[4096];   // 128 rows x 32, chunk-swizzled
    __shared__ unsigned short Bs[4096];

    const int tid  = threadIdx.x;
    const int lane = tid & 63;
    const int wave = tid >> 6;
    const int quad = lane >> 4, l16 = lane & 15;
    const int wm = (wave >> 1) * 64, wn = (wave & 1) * 64;
    const int swz3 = l16 & 3;

    f32x4 acc[4][4] = {};

    const int c0 = wave * 64 + lane, c1 = c0 + 256;
    const int r0 = c0 >> 2, u0 = ((c0 & 3) ^ (r0 & 3)) * 8;
    const int r1 = c1 >> 2, u1 = ((c1 & 3) ^ (r1 & 3)) * 8;
    const int lb0 = (wave * 64) * 8, lb1 = lb0 + 2048;

    for (int kt = 0; kt < D_MODEL; kt += 32) {
        __syncthreads();
        stage16(&xb[(size_t)(m0 + r0) * D_MODEL + kt + u0], As + lb0);
        stage16(&xb[(size_t)(m0 + r1) * D_MODEL + kt + u1], As + lb1);
        stage16(&W [(size_t)(n0 + r0) * D_MODEL + kt + u0], Bs + lb0);
        stage16(&W [(size_t)(n0 + r1) * D_MODEL + kt + u1], Bs + lb1);
        __syncthreads();

        bf16x8 af[4], bfr[4];
        for (int mi = 0; mi < 4; mi++)
            af[mi] = *(const bf16x8*)&As[(wm + mi * 16 + l16) * 32 + (quad ^ swz3) * 8];
        for (int ni = 0; ni < 4; ni++)
            bfr[ni] = *(const bf16x8*)&Bs[(wn + ni * 16 + l16) * 32 + (quad ^ swz3) * 8];
        for (int mi = 0; mi < 4; mi++)
            for (int ni = 0; ni < 4; ni++)
                acc[mi][ni] = __builtin_amdgcn_mfma_f32_16x16x32_bf16(af[mi], bfr[ni], acc[mi][ni], 0, 0, 0);
    }

    for (int mi = 0; mi < 4; mi++)
        for (int ni = 0; ni < 4; ni++) {
            u16x4 cv = cvt4(acc[mi][ni]);
            for (int r = 0; r < 4; r++) {
                int row = m0 + wm + mi * 16 + quad * 4 + r;
                int col = n0 + wn + ni * 16 + l16;
                C[(size_t)row * D_MODEL + col] = cv[r];
            }
        }
}

// ---------------- fused per-head transpose + vals zeroing ------------------
// z < 10: K head z, [64][4096] -> [4096][64];  z >= 10: V head z-10,
// [4096][64] -> [64][4096]. grid (64, 1, 20). After reading its source tile
// each block stores zeros over it: Kn+Vn exactly cover the fp32 vals buffer,
// which attn then accumulates into atomically.
__global__ __launch_bounds__(256) void transpose_kv(
    const unsigned short* __restrict__ Kn, unsigned short* __restrict__ Kp,
    const unsigned short* __restrict__ Vn, unsigned short* __restrict__ Vp) {
    __shared__ unsigned short T[64][66];
    const int z = blockIdx.z;
    const unsigned short* src; unsigned short* dst;
    int R, Cc, r0, c0;
    if (z < 10) { src = Kn; dst = Kp; R = 64;   Cc = 4096; r0 = 0; c0 = blockIdx.x * 64; }
    else        { src = Vn; dst = Vp; R = 4096; Cc = 64;   r0 = blockIdx.x * 64; c0 = 0; }
    const size_t hb = (size_t)(z % 10) * HSLAB;
    const int t = threadIdx.x;
    const int rr = t >> 3, c8 = (t & 7) * 8;

    for (int hf = 0; hf < 2; hf++) {
        int r = rr + hf * 32;
        bf16x8 v = *(const bf16x8*)&src[hb + (size_t)(r0 + r) * Cc + c0 + c8];
        for (int j = 0; j < 8; j++) T[r][c8 + j] = ((unsigned short*)&v)[j];
    }
    __syncthreads();
    // zero the consumed source tile (this region is the attn fp32 accumulator)
    const bf16x8 zz = {};
    for (int hf = 0; hf < 2; hf++) {
        int r = rr + hf * 32;
        *(bf16x8*)&((unsigned short*)src)[hb + (size_t)(r0 + r) * Cc + c0 + c8] = zz;
    }
    for (int hf = 0; hf < 2; hf++) {
        int oc = rr + hf * 32;
        unsigned short v[8];
        for (int j = 0; j < 8; j++) v[j] = T[c8 + j][oc];
        *(bf16x8*)&dst[hb + (size_t)(c0 + oc) * R + r0 + c8] = *(bf16x8*)v;
    }
}

// ------------------------------- attention ---------------------------------
// grid (320, 3): x = head*32 + qtile(128 rows), y = kpart.
// Uneven split: y0/y1 = 21 iters (1344 keys), y2 = 22 iters (1408 keys).
// 960 blocks, 4/CU LDS cap -> single generation, no tail.
#define PLD 72

__global__ __launch_bounds__(256, 4) void attn(
    const unsigned short* __restrict__ Qb,
    const unsigned short* __restrict__ Kp,   // [h][m][k]
    const unsigned short* __restrict__ Vp,   // [h][k][m]
    float* __restrict__ vals,                // pre-zeroed (by transpose_kv)
    float* __restrict__ l_tot) {             // pre-zeroed (by cvt_all)
    const int h  = blockIdx.x >> 5;
    const int qt = blockIdx.x & 31;
    const int kbase = blockIdx.y * 1344;
    const int niter = 21 + (blockIdx.y >> 1);
    const int lane = threadIdx.x & 63;
    const int wave = threadIdx.x >> 6;
    const int quad = lane >> 4, l16 = lane & 15;
    const size_t hoff = (size_t)h * HSLAB;

    __shared__ unsigned short Kt[4096];          // 64x64, unit-swizzled
    __shared__ unsigned short Vt[4096];
    __shared__ unsigned short Pb[4][32 * PLD];
    unsigned short* Pw = &Pb[wave][0];

    const int qbase = qt * 128 + wave * 32;
    bf16x8 qf[2][2];
    for (int g = 0; g < 2; g++)
        for (int kh = 0; kh < 2; kh++)
            qf[g][kh] = *(const bf16x8*)&Qb[hoff + (size_t)(qbase + g * 16 + l16) * DK + kh * 32 + quad * 8];

    f32x4 o[2][4] = {};
    float lsum[2] = {0.f, 0.f};

    // staging: 8 instrs of 64 chunks; chunk c: row=c>>3, unit=(c&7)^(row&7)
    const int s0 = wave * 128 + lane;
    const int s1 = s0 + 64;
    const int kr0 = s0 >> 3, kc0 = (s0 & 7) ^ (kr0 & 7);
    const int kr1 = s1 >> 3, kc1 = (s1 & 7) ^ (kr1 & 7);
    const int swz = l16 & 7;

    for (int it = 0; it < niter; it++) {
        const int m0 = kbase + it * 64;
        __syncthreads();
        stage16(Kp + hoff + (size_t)(m0 + kr0) * DK + kc0 * 8, Kt + wave * 1024);
        stage16(Kp + hoff + (size_t)(m0 + kr1) * DK + kc1 * 8, Kt + wave * 1024 + 512);
        stage16(Vp + hoff + (size_t)kr0 * N_TOK + m0 + kc0 * 8, Vt + wave * 1024);
        stage16(Vp + hoff + (size_t)kr1 * N_TOK + m0 + kc1 * 8, Vt + wave * 1024 + 512);
        __syncthreads();

        // ---- S^T tiles: A = K rows (key), B = Q rows (q) ----
        for (int ni = 0; ni < 4; ni++) {
            const int krow = ni * 16 + l16;
            bf16x8 a0 = *(const bf16x8*)&Kt[krow * 64 + ((0 + quad) ^ swz) * 8];
            bf16x8 a1 = *(const bf16x8*)&Kt[krow * 64 + ((4 + quad) ^ swz) * 8];
            for (int g = 0; g < 2; g++) {
                f32x4 s = {};
                s = __builtin_amdgcn_mfma_f32_16x16x32_bf16(a0, qf[g][0], s, 0, 0, 0);
                s = __builtin_amdgcn_mfma_f32_16x16x32_bf16(a1, qf[g][1], s, 0, 0, 0);
                // lane holds S^T[key=ni*16+quad*4+r][q=g*16+l16]
                f32x4 pv;
                for (int r = 0; r < 4; r++) {
                    pv[r] = exp2f(s[r] * EXP2SCL);
                    lsum[g] += pv[r];
                }
                *(u16x4*)&Pw[(g * 16 + l16) * PLD + ni * 16 + quad * 4] = cvt4(pv);
            }
        }

        // ---- P A-fragments (conflict-free b128) ----
        bf16x8 pf[2][2];
        for (int g = 0; g < 2; g++)
            for (int mh = 0; mh < 2; mh++)
                pf[g][mh] = *(const bf16x8*)&Pw[(g * 16 + l16) * PLD + mh * 32 + quad * 8];

        // ---- O += P * V : B = V rows (dk) ----
        for (int nd = 0; nd < 4; nd++) {
            const int vrow = nd * 16 + l16;
            bf16x8 b0 = *(const bf16x8*)&Vt[vrow * 64 + ((0 + quad) ^ swz) * 8];
            bf16x8 b1 = *(const bf16x8*)&Vt[vrow * 64 + ((4 + quad) ^ swz) * 8];
            for (int g = 0; g < 2; g++) {
                o[g][nd] = __builtin_amdgcn_mfma_f32_16x16x32_bf16(pf[g][0], b0, o[g][nd], 0, 0, 0);
                o[g][nd] = __builtin_amdgcn_mfma_f32_16x16x32_bf16(pf[g][1], b1, o[g][nd], 0, 0, 0);
            }
        }
    }

    // row sums: reduce over quads (lane bits 4,5)
    for (int g = 0; g < 2; g++) {
        float v = lsum[g];
        v += __shfl_xor(v, 16, 64);
        v += __shfl_xor(v, 32, 64);
        if (lane < 16)
            atomicAdd(&l_tot[(h << 12) + qbase + g * 16 + l16], v);
    }

    // O: C-layout row = q offset quad*4+r, col = dk = nd*16+l16
    for (int g = 0; g < 2; g++)
        for (int nd = 0; nd < 4; nd++)
            for (int r = 0; r < 4; r++) {
                int q = qbase + g * 16 + quad * 4 + r;
                atomicAdd(&vals[hoff + (size_t)q * DK + nd * 16 + l16], o[g][nd][r]);
            }
}

// ----------------- deferred normalize + residual + LayerNorm ---------------
__global__ __launch_bounds__(256) void ln_kernel(
    const float* __restrict__ vals, const float* __restrict__ l_tot,
    const float* __restrict__ x,
    const float* __restrict__ gamma, const float* __restrict__ beta,
    float* __restrict__ out) {
    const int wave = threadIdx.x >> 6, lane = threadIdx.x & 63;
    const int row  = blockIdx.x * 4 + wave;
    const float* v  = vals + (size_t)row * D_MODEL;
    const float* xr = x    + (size_t)row * D_MODEL;

    float t[10];
    float s = 0.f;
    for (int i = 0; i < 10; i++) {
        float linv = 1.0f / l_tot[row * 10 + i];
        t[i] = v[lane + i * 64] * linv + xr[lane + i * 64];
        s += t[i];
    }
    for (int off = 32; off; off >>= 1) s += __shfl_xor(s, off, 64);
    float mean = s * (1.0f / 640.0f);
    float s2 = 0.f;
    for (int i = 0; i < 10; i++) { float d = t[i] - mean; s2 += d * d; }
    for (int off = 32; off; off >>= 1) s2 += __shfl_xor(s2, off, 64);
    float inv = rsqrtf(s2 * (1.0f / 640.0f) + 1e-5f);

    float* orow = out + (size_t)row * D_MODEL;
    for (int i = 0; i < 10; i++) {
        int c = lane + i * 64;
        orow[c] = (t[i] - mean) * inv * gamma[c] + beta[c];
    }
}

// ------------------------------- launcher ----------------------------------
extern "C" void kernel_launch(void* const* d_in, const int* in_sizes, int n_in,
                              void* d_out, int out_size, void* d_ws, size_t ws_size,
                              hipStream_t stream) {
    const float* x     = (const float*)d_in[0];
    const float* Wq    = (const float*)d_in[1];
    const float* Wk    = (const float*)d_in[2];
    const float* Wv    = (const float*)d_in[3];
    const float* gamma = (const float*)d_in[4];
    const float* beta  = (const float*)d_in[5];
    float* out = (float*)d_out;

    char* ws = (char*)d_ws;
    unsigned short* xb  = (unsigned short*)(ws);               // 5,242,880 B
    unsigned short* wqb = (unsigned short*)(ws + 5242880);
    unsigned short* wkb = (unsigned short*)(ws + 6062080);
    unsigned short* wvb = (unsigned short*)(ws + 6881280);
    unsigned short* Qb  = (unsigned short*)(ws + 7700480);
    unsigned short* Kp  = (unsigned short*)(ws + 12943360);    // K' [h][m][k]
    unsigned short* Vp  = (unsigned short*)(ws + 18186240);    // V' [h][k][m]
    unsigned short* Kn  = (unsigned short*)(ws + 23429120);    // aliases vals
    unsigned short* Vn  = (unsigned short*)(ws + 28672000);    //  (exactly)
    float*          vals  = (float*)(ws + 23429120);           // 10,485,760 B
    float*          l_tot = (float*)(ws + 33914880);           //   163,840 B

    cvt_all<<<3800, 256, 0, stream>>>(x, Wq, Wk, Wv, xb, wqb, wkb, wvb,
                                      (f32x4*)l_tot);

    gemm_qkv<<<dim3(5, 32, 3), 256, 0, stream>>>(xb, wqb, wkb, wvb, Qb, Kn, Vn);

    transpose_kv<<<dim3(64, 1, 20), 256, 0, stream>>>(Kn, Kp, Vn, Vp);

    attn<<<dim3(320, 3), 256, 0, stream>>>(Qb, Kp, Vp, vals, l_tot);
    ln_kernel<<<1024, 256, 0, stream>>>(vals, l_tot, x, gamma, beta, out);
}

// Round 7
// 167.436 us; speedup vs baseline: 1.2361x; 1.0927x over previous
//
#include <hip/hip_runtime.h>

// ---------------------------------------------------------------------------
// MHABlock: fused cvt (+l_tot zero, +softmax scale folded into Wq) ->
// QKV GEMM (global_load_lds staging) -> fused K/V transpose (+vals zero) ->
// split-K(3) flash attention (no-max online softmax, raw v_exp, ones-MFMA
// row sums) -> deferred normalize + residual + LayerNorm.
// ---------------------------------------------------------------------------

typedef __bf16 bf16x8 __attribute__((ext_vector_type(8)));
typedef __bf16 bf16x4 __attribute__((ext_vector_type(4)));
typedef float  f32x4  __attribute__((ext_vector_type(4)));
typedef unsigned short u16x4 __attribute__((ext_vector_type(4)));
typedef short          s16x8 __attribute__((ext_vector_type(8)));

#define N_TOK   4096
#define D_MODEL 640
#define DK      64
#define HSLAB   (N_TOK * DK)
// exp(s/64) = 2^(s * log2(e)/64); folded into Wq at cvt time
#define EXP2SCL 0.022542110f

#if __has_builtin(__builtin_amdgcn_exp2f)
#define EXP2(x) __builtin_amdgcn_exp2f(x)
#else
#define EXP2(x) exp2f(x)
#endif

__device__ __forceinline__ void stage16(const unsigned short* g, unsigned short* lds_uniform) {
    __builtin_amdgcn_global_load_lds(
        (const __attribute__((address_space(1))) unsigned int*)g,
        (__attribute__((address_space(3))) unsigned int*)lds_uniform, 16, 0, 0);
}

// packed f32x4 -> bf16x4
__device__ __forceinline__ u16x4 cvt4(f32x4 v) {
    return __builtin_bit_cast(u16x4, __builtin_convertvector(v, bf16x4));
}

// ---------- fused fp32 -> bf16 (x, Wq*scale, Wk, Wv) + l_tot zeroing -------
// grid 3800: [0,655360) x | [655360,962560) weights | [962560,972800) l_tot=0
__global__ __launch_bounds__(256) void cvt_all(const float* __restrict__ x,
                                               const float* __restrict__ w0,
                                               const float* __restrict__ w1,
                                               const float* __restrict__ w2,
                                               unsigned short* __restrict__ xb,
                                               unsigned short* __restrict__ d0,
                                               unsigned short* __restrict__ d1,
                                               unsigned short* __restrict__ d2,
                                               f32x4* __restrict__ ltot4) {
    int i = blockIdx.x * 256 + threadIdx.x;
    if (i >= 962560) { ltot4[i - 962560] = (f32x4){0.f, 0.f, 0.f, 0.f}; return; }
    const float* s; unsigned short* d; int off; float scl = 1.0f;
    if (i < 655360) { s = x; d = xb; off = i; }
    else {
        int j = i - 655360;
        int w = j / 102400; off = j - w * 102400;
        s = (w == 0) ? w0 : (w == 1) ? w1 : w2;
        d = (w == 0) ? d0 : (w == 1) ? d1 : d2;
        if (w == 0) scl = EXP2SCL;   // Q only feeds QK^T: pre-scale softmax
    }
    f32x4 v = ((const f32x4*)s)[off];
    v[0] *= scl; v[1] *= scl; v[2] *= scl; v[3] *= scl;
    ((u16x4*)d)[off] = cvt4(v);
}

// ------------------------ QKV NT-GEMM: C = x @ W^T -------------------------
// M=4096, N=640, K=640. 128x128 tile, BK=32, 4 waves each 64x64.
__global__ __launch_bounds__(256, 2) void gemm_qkv(
    const unsigned short* __restrict__ xb,
    const unsigned short* __restrict__ wq,
    const unsigned short* __restrict__ wk,
    const unsigned short* __restrict__ wv,
    unsigned short* __restrict__ Qo,
    unsigned short* __restrict__ Ko,
    unsigned short* __restrict__ Vo) {
    const int mode = blockIdx.z;
    const unsigned short* W = (mode == 0) ? wq : (mode == 1) ? wk : wv;
    unsigned short*       C = (mode == 0) ? Qo : (mode == 1) ? Ko : Vo;
    const int m0 = blockIdx.y * 128;
    const int n0 = blockIdx.x * 128;

    __shared__ unsigned short As[4096];   // 128 rows x 32, chunk-swizzled
    __shared__ unsigned short Bs[4096];

    const int tid  = threadIdx.x;
    const int lane = tid & 63;
    const int wave = tid >> 6;
    const int quad = lane >> 4, l16 = lane & 15;
    const int wm = (wave >> 1) * 64, wn = (wave & 1) * 64;
    const int swz3 = l16 & 3;

    f32x4 acc[4][4] = {};

    const int c0 = wave * 64 + lane, c1 = c0 + 256;
    const int r0 = c0 >> 2, u0 = ((c0 & 3) ^ (r0 & 3)) * 8;
    const int r1 = c1 >> 2, u1 = ((c1 & 3) ^ (r1 & 3)) * 8;
    const int lb0 = (wave * 64) * 8, lb1 = lb0 + 2048;

    for (int kt = 0; kt < D_MODEL; kt += 32) {
        __syncthreads();
        stage16(&xb[(size_t)(m0 + r0) * D_MODEL + kt + u0], As + lb0);
        stage16(&xb[(size_t)(m0 + r1) * D_MODEL + kt + u1], As + lb1);
        stage16(&W [(size_t)(n0 + r0) * D_MODEL + kt + u0], Bs + lb0);
        stage16(&W [(size_t)(n0 + r1) * D_MODEL + kt + u1], Bs + lb1);
        __syncthreads();

        bf16x8 af[4], bfr[4];
        for (int mi = 0; mi < 4; mi++)
            af[mi] = *(const bf16x8*)&As[(wm + mi * 16 + l16) * 32 + (quad ^ swz3) * 8];
        for (int ni = 0; ni < 4; ni++)
            bfr[ni] = *(const bf16x8*)&Bs[(wn + ni * 16 + l16) * 32 + (quad ^ swz3) * 8];
        for (int mi = 0; mi < 4; mi++)
            for (int ni = 0; ni < 4; ni++)
                acc[mi][ni] = __builtin_amdgcn_mfma_f32_16x16x32_bf16(af[mi], bfr[ni], acc[mi][ni], 0, 0, 0);
    }

    for (int mi = 0; mi < 4; mi++)
        for (int ni = 0; ni < 4; ni++) {
            u16x4 cv = cvt4(acc[mi][ni]);
            for (int r = 0; r < 4; r++) {
                int row = m0 + wm + mi * 16 + quad * 4 + r;
                int col = n0 + wn + ni * 16 + l16;
                C[(size_t)row * D_MODEL + col] = cv[r];
            }
        }
}

// ---------------- fused per-head transpose + vals zeroing ------------------
__global__ __launch_bounds__(256) void transpose_kv(
    const unsigned short* __restrict__ Kn, unsigned short* __restrict__ Kp,
    const unsigned short* __restrict__ Vn, unsigned short* __restrict__ Vp) {
    __shared__ unsigned short T[64][66];
    const int z = blockIdx.z;
    const unsigned short* src; unsigned short* dst;
    int R, Cc, r0, c0;
    if (z < 10) { src = Kn; dst = Kp; R = 64;   Cc = 4096; r0 = 0; c0 = blockIdx.x * 64; }
    else        { src = Vn; dst = Vp; R = 4096; Cc = 64;   r0 = blockIdx.x * 64; c0 = 0; }
    const size_t hb = (size_t)(z % 10) * HSLAB;
    const int t = threadIdx.x;
    const int rr = t >> 3, c8 = (t & 7) * 8;

    for (int hf = 0; hf < 2; hf++) {
        int r = rr + hf * 32;
        bf16x8 v = *(const bf16x8*)&src[hb + (size_t)(r0 + r) * Cc + c0 + c8];
        for (int j = 0; j < 8; j++) T[r][c8 + j] = ((unsigned short*)&v)[j];
    }
    __syncthreads();
    // zero the consumed source tile (this region is the attn fp32 accumulator)
    const bf16x8 zz = {};
    for (int hf = 0; hf < 2; hf++) {
        int r = rr + hf * 32;
        *(bf16x8*)&((unsigned short*)src)[hb + (size_t)(r0 + r) * Cc + c0 + c8] = zz;
    }
    for (int hf = 0; hf < 2; hf++) {
        int oc = rr + hf * 32;
        unsigned short v[8];
        for (int j = 0; j < 8; j++) v[j] = T[c8 + j][oc];
        *(bf16x8*)&dst[hb + (size_t)(c0 + oc) * R + r0 + c8] = *(bf16x8*)v;
    }
}

// ------------------------------- attention ---------------------------------
// grid (320, 3): x = head*32 + qtile(128 rows), y = kpart (21/21/22 iters).
#define PLD 72

__global__ __launch_bounds__(256, 4) void attn(
    const unsigned short* __restrict__ Qb,
    const unsigned short* __restrict__ Kp,   // [h][m][k]
    const unsigned short* __restrict__ Vp,   // [h][k][m]
    float* __restrict__ vals,                // pre-zeroed (by transpose_kv)
    float* __restrict__ l_tot) {             // pre-zeroed (by cvt_all)
    const int h  = blockIdx.x >> 5;
    const int qt = blockIdx.x & 31;
    const int kbase = blockIdx.y * 1344;
    const int niter = 21 + (blockIdx.y >> 1);
    const int lane = threadIdx.x & 63;
    const int wave = threadIdx.x >> 6;
    const int quad = lane >> 4, l16 = lane & 15;
    const size_t hoff = (size_t)h * HSLAB;

    __shared__ unsigned short Kt[4096];          // 64x64, unit-swizzled
    __shared__ unsigned short Vt[4096];
    __shared__ unsigned short Pb[4][32 * PLD];
    unsigned short* Pw = &Pb[wave][0];

    const int qbase = qt * 128 + wave * 32;
    bf16x8 qf[2][2];
    for (int g = 0; g < 2; g++)
        for (int kh = 0; kh < 2; kh++)
            qf[g][kh] = *(const bf16x8*)&Qb[hoff + (size_t)(qbase + g * 16 + l16) * DK + kh * 32 + quad * 8];

    f32x4 o[2][4] = {};
    f32x4 ol[2] = {};
    const bf16x8 ones = __builtin_bit_cast(bf16x8, (s16x8)(short)0x3F80);

    // staging: 8 instrs of 64 chunks; chunk c: row=c>>3, unit=(c&7)^(row&7)
    const int s0 = wave * 128 + lane;
    const int s1 = s0 + 64;
    const int kr0 = s0 >> 3, kc0 = (s0 & 7) ^ (kr0 & 7);
    const int kr1 = s1 >> 3, kc1 = (s1 & 7) ^ (kr1 & 7);
    const int swz = l16 & 7;

    for (int it = 0; it < niter; it++) {
        const int m0 = kbase + it * 64;
        __syncthreads();
        stage16(Kp + hoff + (size_t)(m0 + kr0) * DK + kc0 * 8, Kt + wave * 1024);
        stage16(Kp + hoff + (size_t)(m0 + kr1) * DK + kc1 * 8, Kt + wave * 1024 + 512);
        stage16(Vp + hoff + (size_t)kr0 * N_TOK + m0 + kc0 * 8, Vt + wave * 1024);
        stage16(Vp + hoff + (size_t)kr1 * N_TOK + m0 + kc1 * 8, Vt + wave * 1024 + 512);
        __syncthreads();

        // ---- S^T tiles: A = K rows (key), B = Q rows (q, pre-scaled) ----
        for (int ni = 0; ni < 4; ni++) {
            const int krow = ni * 16 + l16;
            bf16x8 a0 = *(const bf16x8*)&Kt[krow * 64 + ((0 + quad) ^ swz) * 8];
            bf16x8 a1 = *(const bf16x8*)&Kt[krow * 64 + ((4 + quad) ^ swz) * 8];
            for (int g = 0; g < 2; g++) {
                f32x4 s = {};
                s = __builtin_amdgcn_mfma_f32_16x16x32_bf16(a0, qf[g][0], s, 0, 0, 0);
                s = __builtin_amdgcn_mfma_f32_16x16x32_bf16(a1, qf[g][1], s, 0, 0, 0);
                // lane holds S^T[key=ni*16+quad*4+r][q=g*16+l16]
                f32x4 pv;
                for (int r = 0; r < 4; r++) pv[r] = EXP2(s[r]);
                *(u16x4*)&Pw[(g * 16 + l16) * PLD + ni * 16 + quad * 4] = cvt4(pv);
            }
        }

        // ---- P A-fragments (conflict-free b128) ----
        bf16x8 pf[2][2];
        for (int g = 0; g < 2; g++)
            for (int mh = 0; mh < 2; mh++)
                pf[g][mh] = *(const bf16x8*)&Pw[(g * 16 + l16) * PLD + mh * 32 + quad * 8];

        // row sums via ones-MFMA (C row = q offset, cols identical)
        for (int g = 0; g < 2; g++) {
            ol[g] = __builtin_amdgcn_mfma_f32_16x16x32_bf16(pf[g][0], ones, ol[g], 0, 0, 0);
            ol[g] = __builtin_amdgcn_mfma_f32_16x16x32_bf16(pf[g][1], ones, ol[g], 0, 0, 0);
        }

        // ---- O += P * V : B = V rows (dk) ----
        for (int nd = 0; nd < 4; nd++) {
            const int vrow = nd * 16 + l16;
            bf16x8 b0 = *(const bf16x8*)&Vt[vrow * 64 + ((0 + quad) ^ swz) * 8];
            bf16x8 b1 = *(const bf16x8*)&Vt[vrow * 64 + ((4 + quad) ^ swz) * 8];
            for (int g = 0; g < 2; g++) {
                o[g][nd] = __builtin_amdgcn_mfma_f32_16x16x32_bf16(pf[g][0], b0, o[g][nd], 0, 0, 0);
                o[g][nd] = __builtin_amdgcn_mfma_f32_16x16x32_bf16(pf[g][1], b1, o[g][nd], 0, 0, 0);
            }
        }
    }

    // l: C-layout row = quad*4+r, all cols identical -> write from l16==0
    if (l16 == 0)
        for (int g = 0; g < 2; g++)
            for (int r = 0; r < 4; r++)
                atomicAdd(&l_tot[(h << 12) + qbase + g * 16 + quad * 4 + r], ol[g][r]);

    // O: C-layout row = q offset quad*4+r, col = dk = nd*16+l16
    for (int g = 0; g < 2; g++)
        for (int nd = 0; nd < 4; nd++)
            for (int r = 0; r < 4; r++) {
                int q = qbase + g * 16 + quad * 4 + r;
                atomicAdd(&vals[hoff + (size_t)q * DK + nd * 16 + l16], o[g][nd][r]);
            }
}

// ----------------- deferred normalize + residual + LayerNorm ---------------
__global__ __launch_bounds__(256) void ln_kernel(
    const float* __restrict__ vals, const float* __restrict__ l_tot,
    const float* __restrict__ x,
    const float* __restrict__ gamma, const float* __restrict__ beta,
    float* __restrict__ out) {
    const int wave = threadIdx.x >> 6, lane = threadIdx.x & 63;
    const int row  = blockIdx.x * 4 + wave;
    const float* v  = vals + (size_t)row * D_MODEL;
    const float* xr = x    + (size_t)row * D_MODEL;

    float t[10];
    float s = 0.f;
    for (int i = 0; i < 10; i++) {
        float linv = 1.0f / l_tot[row * 10 + i];
        t[i] = v[lane + i * 64] * linv + xr[lane + i * 64];
        s += t[i];
    }
    for (int off = 32; off; off >>= 1) s += __shfl_xor(s, off, 64);
    float mean = s * (1.0f / 640.0f);
    float s2 = 0.f;
    for (int i = 0; i < 10; i++) { float d = t[i] - mean; s2 += d * d; }
    for (int off = 32; off; off >>= 1) s2 += __shfl_xor(s2, off, 64);
    float inv = rsqrtf(s2 * (1.0f / 640.0f) + 1e-5f);

    float* orow = out + (size_t)row * D_MODEL;
    for (int i = 0; i < 10; i++) {
        int c = lane + i * 64;
        orow[c] = (t[i] - mean) * inv * gamma[c] + beta[c];
    }
}

// ------------------------------- launcher ----------------------------------
extern "C" void kernel_launch(void* const* d_in, const int* in_sizes, int n_in,
                              void* d_out, int out_size, void* d_ws, size_t ws_size,
                              hipStream_t stream) {
    const float* x     = (const float*)d_in[0];
    const float* Wq    = (const float*)d_in[1];
    const float* Wk    = (const float*)d_in[2];
    const float* Wv    = (const float*)d_in[3];
    const float* gamma = (const float*)d_in[4];
    const float* beta  = (const float*)d_in[5];
    float* out = (float*)d_out;

    char* ws = (char*)d_ws;
    unsigned short* xb  = (unsigned short*)(ws);               // 5,242,880 B
    unsigned short* wqb = (unsigned short*)(ws + 5242880);
    unsigned short* wkb = (unsigned short*)(ws + 6062080);
    unsigned short* wvb = (unsigned short*)(ws + 6881280);
    unsigned short* Qb  = (unsigned short*)(ws + 7700480);
    unsigned short* Kp  = (unsigned short*)(ws + 12943360);    // K' [h][m][k]
    unsigned short* Vp  = (unsigned short*)(ws + 18186240);    // V' [h][k][m]
    unsigned short* Kn  = (unsigned short*)(ws + 23429120);    // aliases vals
    unsigned short* Vn  = (unsigned short*)(ws + 28672000);    //  (exactly)
    float*          vals  = (float*)(ws + 23429120);           // 10,485,760 B
    float*          l_tot = (float*)(ws + 33914880);           //   163,840 B

    cvt_all<<<3800, 256, 0, stream>>>(x, Wq, Wk, Wv, xb, wqb, wkb, wvb,
                                      (f32x4*)l_tot);

    gemm_qkv<<<dim3(5, 32, 3), 256, 0, stream>>>(xb, wqb, wkb, wvb, Qb, Kn, Vn);

    transpose_kv<<<dim3(64, 1, 20), 256, 0, stream>>>(Kn, Kp, Vn, Vp);

    attn<<<dim3(320, 3), 256, 0, stream>>>(Qb, Kp, Vp, vals, l_tot);
    ln_kernel<<<1024, 256, 0, stream>>>(vals, l_tot, x, gamma, beta, out);
}

// Round 8
// 166.196 us; speedup vs baseline: 1.2453x; 1.0075x over previous
//
#include <hip/hip_runtime.h>
#if __has_include(<hip/hip_fp8.h>)
#include <hip/hip_fp8.h>
#endif

// ---------------------------------------------------------------------------
// MHABlock: cvt (+l_tot zero, sqrt-softmax-scale folded into Wq AND Wk) ->
// QKV GEMM (bf16, global_load_lds staging) -> fused K/V transpose + fp8
// convert (+Q->fp8, +vals zero) -> split-K(3) fp8 flash attention
// (no-max online softmax, v_exp, ones-MFMA row sums, Bk=128, bank-uniform
// XOR LDS layouts) -> deferred normalize + residual + LayerNorm.
// All reshape quirks handled flat (head = flatidx>>18).
// ---------------------------------------------------------------------------

typedef __bf16 bf16x8 __attribute__((ext_vector_type(8)));
typedef __bf16 bf16x4 __attribute__((ext_vector_type(4)));
typedef float  f32x4  __attribute__((ext_vector_type(4)));
typedef unsigned short u16x4 __attribute__((ext_vector_type(4)));
typedef unsigned int   u32x4 __attribute__((ext_vector_type(4)));

#define N_TOK   4096
#define D_MODEL 640
#define DK      64
#define HSLAB   (N_TOK * DK)
// sqrt(log2(e)/64): folded into BOTH Wq and Wk -> logits arrive base-2 scaled
#define SQS 0.15014030f

#if __has_builtin(__builtin_amdgcn_exp2f)
#define EXP2(x) __builtin_amdgcn_exp2f(x)
#else
#define EXP2(x) exp2f(x)
#endif

__device__ __forceinline__ void stage16(const void* g, void* lds_uniform) {
    __builtin_amdgcn_global_load_lds(
        (const __attribute__((address_space(1))) unsigned int*)g,
        (__attribute__((address_space(3))) unsigned int*)lds_uniform, 16, 0, 0);
}

__device__ __forceinline__ u16x4 cvt4(f32x4 v) {
    return __builtin_bit_cast(u16x4, __builtin_convertvector(v, bf16x4));
}

// packed f32x4 -> 4x e4m3fn bytes
__device__ __forceinline__ unsigned int pk_fp8(f32x4 v) {
#if __has_builtin(__builtin_amdgcn_cvt_pk_fp8_f32)
    int r = 0;
    r = __builtin_amdgcn_cvt_pk_fp8_f32(v[0], v[1], r, false);
    r = __builtin_amdgcn_cvt_pk_fp8_f32(v[2], v[3], r, true);
    return (unsigned int)r;
#else
    union { unsigned char b[4]; unsigned int u; } x;
    x.b[0] = __hip_fp8_e4m3(v[0]).__x;
    x.b[1] = __hip_fp8_e4m3(v[1]).__x;
    x.b[2] = __hip_fp8_e4m3(v[2]).__x;
    x.b[3] = __hip_fp8_e4m3(v[3]).__x;
    return x.u;
#endif
}

// ---------- fused fp32 -> bf16 (x, Wq*s, Wk*s, Wv) + l_tot zeroing ---------
__global__ __launch_bounds__(256) void cvt_all(const float* __restrict__ x,
                                               const float* __restrict__ w0,
                                               const float* __restrict__ w1,
                                               const float* __restrict__ w2,
                                               unsigned short* __restrict__ xb,
                                               unsigned short* __restrict__ d0,
                                               unsigned short* __restrict__ d1,
                                               unsigned short* __restrict__ d2,
                                               f32x4* __restrict__ ltot4) {
    int i = blockIdx.x * 256 + threadIdx.x;
    if (i >= 962560) { ltot4[i - 962560] = (f32x4){0.f, 0.f, 0.f, 0.f}; return; }
    const float* s; unsigned short* d; int off; float scl = 1.0f;
    if (i < 655360) { s = x; d = xb; off = i; }
    else {
        int j = i - 655360;
        int w = j / 102400; off = j - w * 102400;
        s = (w == 0) ? w0 : (w == 1) ? w1 : w2;
        d = (w == 0) ? d0 : (w == 1) ? d1 : d2;
        if (w < 2) scl = SQS;   // Wq, Wk carry sqrt of softmax scale
    }
    f32x4 v = ((const f32x4*)s)[off];
    v[0] *= scl; v[1] *= scl; v[2] *= scl; v[3] *= scl;
    ((u16x4*)d)[off] = cvt4(v);
}

// ------------------------ QKV NT-GEMM: C = x @ W^T -------------------------
__global__ __launch_bounds__(256, 2) void gemm_qkv(
    const unsigned short* __restrict__ xb,
    const unsigned short* __restrict__ wq,
    const unsigned short* __restrict__ wk,
    const unsigned short* __restrict__ wv,
    unsigned short* __restrict__ Qo,
    unsigned short* __restrict__ Ko,
    unsigned short* __restrict__ Vo) {
    const int mode = blockIdx.z;
    const unsigned short* W = (mode == 0) ? wq : (mode == 1) ? wk : wv;
    unsigned short*       C = (mode == 0) ? Qo : (mode == 1) ? Ko : Vo;
    const int m0 = blockIdx.y * 128;
    const int n0 = blockIdx.x * 128;

    __shared__ unsigned short As[4096];
    __shared__ unsigned short Bs[4096];

    const int tid  = threadIdx.x;
    const int lane = tid & 63;
    const int wave = tid >> 6;
    const int quad = lane >> 4, l16 = lane & 15;
    const int wm = (wave >> 1) * 64, wn = (wave & 1) * 64;
    const int swz3 = l16 & 3;

    f32x4 acc[4][4] = {};

    const int c0 = wave * 64 + lane, c1 = c0 + 256;
    const int r0 = c0 >> 2, u0 = ((c0 & 3) ^ (r0 & 3)) * 8;
    const int r1 = c1 >> 2, u1 = ((c1 & 3) ^ (r1 & 3)) * 8;
    const int lb0 = (wave * 64) * 8, lb1 = lb0 + 2048;

    for (int kt = 0; kt < D_MODEL; kt += 32) {
        __syncthreads();
        stage16(&xb[(size_t)(m0 + r0) * D_MODEL + kt + u0], As + lb0);
        stage16(&xb[(size_t)(m0 + r1) * D_MODEL + kt + u1], As + lb1);
        stage16(&W [(size_t)(n0 + r0) * D_MODEL + kt + u0], Bs + lb0);
        stage16(&W [(size_t)(n0 + r1) * D_MODEL + kt + u1], Bs + lb1);
        __syncthreads();

        bf16x8 af[4], bfr[4];
        for (int mi = 0; mi < 4; mi++)
            af[mi] = *(const bf16x8*)&As[(wm + mi * 16 + l16) * 32 + (quad ^ swz3) * 8];
        for (int ni = 0; ni < 4; ni++)
            bfr[ni] = *(const bf16x8*)&Bs[(wn + ni * 16 + l16) * 32 + (quad ^ swz3) * 8];
        for (int mi = 0; mi < 4; mi++)
            for (int ni = 0; ni < 4; ni++)
                acc[mi][ni] = __builtin_amdgcn_mfma_f32_16x16x32_bf16(af[mi], bfr[ni], acc[mi][ni], 0, 0, 0);
    }

    for (int mi = 0; mi < 4; mi++)
        for (int ni = 0; ni < 4; ni++) {
            u16x4 cv = cvt4(acc[mi][ni]);
            for (int r = 0; r < 4; r++) {
                int row = m0 + wm + mi * 16 + quad * 4 + r;
                int col = n0 + wn + ni * 16 + l16;
                C[(size_t)row * D_MODEL + col] = cv[r];
            }
        }
}

// ------ fused per-head transpose -> fp8 (K',V') + Q->fp8 + vals zero -------
// z<10: K head z [64][4096]->fp8 [4096][64]; z in [10,20): V head z-10
// [4096][64]->fp8 [64][4096]; z in [20,30): Q head z-20 flat bf16->fp8.
__global__ __launch_bounds__(256) void transpose_kv(
    const unsigned short* __restrict__ Kn, unsigned char* __restrict__ Kp8,
    const unsigned short* __restrict__ Vn, unsigned char* __restrict__ Vp8,
    const unsigned short* __restrict__ Qn, unsigned char* __restrict__ Qf8) {
    const int z = blockIdx.z;
    const int t = threadIdx.x;

    if (z >= 20) {   // Q convert: head slab, flat
        const size_t base = (size_t)(z - 20) * HSLAB + blockIdx.x * 4096 + t * 16;
        bf16x8 v0 = *(const bf16x8*)&Qn[base];
        bf16x8 v1 = *(const bf16x8*)&Qn[base + 8];
        f32x4 a = {(float)v0[0], (float)v0[1], (float)v0[2], (float)v0[3]};
        f32x4 b = {(float)v0[4], (float)v0[5], (float)v0[6], (float)v0[7]};
        f32x4 c = {(float)v1[0], (float)v1[1], (float)v1[2], (float)v1[3]};
        f32x4 d = {(float)v1[4], (float)v1[5], (float)v1[6], (float)v1[7]};
        u32x4 o = {pk_fp8(a), pk_fp8(b), pk_fp8(c), pk_fp8(d)};
        *(u32x4*)&Qf8[base] = o;
        return;
    }

    __shared__ unsigned short T[64][66];
    const unsigned short* src; unsigned char* dst;
    int R, Cc, r0, c0;
    if (z < 10) { src = Kn; dst = Kp8; R = 64;   Cc = 4096; r0 = 0; c0 = blockIdx.x * 64; }
    else        { src = Vn; dst = Vp8; R = 4096; Cc = 64;   r0 = blockIdx.x * 64; c0 = 0; }
    const size_t hb = (size_t)(z % 10) * HSLAB;
    const int rr = t >> 3, c8 = (t & 7) * 8;

    for (int hf = 0; hf < 2; hf++) {
        int r = rr + hf * 32;
        bf16x8 v = *(const bf16x8*)&src[hb + (size_t)(r0 + r) * Cc + c0 + c8];
        for (int j = 0; j < 8; j++) T[r][c8 + j] = ((unsigned short*)&v)[j];
    }
    __syncthreads();
    // zero the consumed source tile (Kn+Vn exactly cover the fp32 vals buf)
    const bf16x8 zz = {};
    for (int hf = 0; hf < 2; hf++) {
        int r = rr + hf * 32;
        *(bf16x8*)&((unsigned short*)src)[hb + (size_t)(r0 + r) * Cc + c0 + c8] = zz;
    }
    for (int hf = 0; hf < 2; hf++) {
        int oc = rr + hf * 32;
        f32x4 lo, hi;
        for (int j = 0; j < 4; j++) {
            lo[j] = __builtin_bit_cast(float, (unsigned int)T[c8 + j][oc] << 16);
            hi[j] = __builtin_bit_cast(float, (unsigned int)T[c8 + 4 + j][oc] << 16);
        }
        uint2 ov; ov.x = pk_fp8(lo); ov.y = pk_fp8(hi);
        // R==64 (K'): row=key len 64; R==4096 (V'): row=dk len 4096
        size_t dcol = (z < 10) ? ((size_t)(c0 + oc) * 64 + r0 + c8)
                               : ((size_t)oc * 4096 + r0 + c8);
        *(uint2*)&dst[hb + dcol] = ov;
    }
}

// ------------------------------- attention (fp8) ---------------------------
// grid (320, 3): x = head*32 + qtile(128 rows), y = kpart (11/11/10 tiles
// of 128 keys). 4 waves x 32 q. Per tile: stage K(128x64B)+V(64x128B) fp8,
// S^T = K*Q^T (fp8 MFMA), exp2, P fp8 -> per-wave LDS, ones-MFMA row sums,
// O += P*V. All LDS access bank-uniform via XOR-at-staging layouts.
__global__ __launch_bounds__(256, 4) void attn(
    const unsigned char* __restrict__ Qf8,   // [h][q][dk] fp8 (flat slabs)
    const unsigned char* __restrict__ Kp8,   // [h][key][dk] fp8
    const unsigned char* __restrict__ Vp8,   // [h][dk][key] fp8
    float* __restrict__ vals,                // pre-zeroed (transpose_kv)
    float* __restrict__ l_tot) {             // pre-zeroed (cvt_all)
    const int h  = blockIdx.x >> 5;
    const int qt = blockIdx.x & 31;
    const int ntile = (blockIdx.y == 2) ? 10 : 11;
    const int tile0 = blockIdx.y * 11;
    const int lane = threadIdx.x & 63;
    const int wave = threadIdx.x >> 6;
    const int quad = lane >> 4, l16 = lane & 15;
    const size_t hoff = (size_t)h * HSLAB;

    __shared__ unsigned char sm[32768];
    unsigned char* Kt = sm;                        // 8KB: 128 keys x 64B
    unsigned char* Vt = sm + 8192;                 // 8KB: 64 dk x 128B
    unsigned char* Pw = sm + 16384 + wave * 4096;  // 32 q x 128B per wave

    const int qbase = qt * 128 + wave * 32;
    long qd[2][2];
    for (int g = 0; g < 2; g++) {
        const unsigned char* qp = Qf8 + hoff + (size_t)(qbase + g * 16 + l16) * 64 + quad * 8;
        qd[g][0] = *(const long*)(qp);
        qd[g][1] = *(const long*)(qp + 32);
    }

    f32x4 o[2][4] = {};
    f32x4 ol[2] = {};
    const long ONES8 = 0x3838383838383838L;   // e4m3 1.0 x8

    // staging chunks: LDS chunk c (16B) <- global unit XORed for bank spread
    const int cA = wave * 64 + lane, cB = cA + 256;
    const int kA = cA >> 2, uA = ((cA & 3) ^ (kA & 3)) << 4;
    const int kB = cB >> 2, uB = ((cB & 3) ^ (kB & 3)) << 4;
    const int dA = cA >> 3, wA = ((cA & 7) ^ (dA & 7)) << 4;
    const int dB = cB >> 3, wB = ((cB & 7) ^ (dB & 7)) << 4;

    for (int t = 0; t < ntile; t++) {
        const int keyb = (tile0 + t) << 7;
        __syncthreads();
        stage16(Kp8 + hoff + (size_t)(keyb + kA) * 64 + uA, Kt + wave * 1024);
        stage16(Kp8 + hoff + (size_t)(keyb + kB) * 64 + uB, Kt + 4096 + wave * 1024);
        stage16(Vp8 + hoff + (size_t)dA * N_TOK + keyb + wA, Vt + wave * 1024);
        stage16(Vp8 + hoff + (size_t)dB * N_TOK + keyb + wB, Vt + 4096 + wave * 1024);
        __syncthreads();

        // ---- S^T: A = K rows (key), B = Q (pre-scaled); exp2 -> P fp8 ----
        for (int ni = 0; ni < 8; ni++) {
            const int keyloc = ni * 16 + l16;
            const unsigned char* kp = Kt + keyloc * 64 + (quad & 1) * 8;
            long a0 = *(const long*)(kp + ((((quad >> 1)    ) ^ (keyloc & 3)) << 4));
            long a1 = *(const long*)(kp + (((2 + (quad >> 1)) ^ (keyloc & 3)) << 4));
            for (int g = 0; g < 2; g++) {
                f32x4 s = {};
                s = __builtin_amdgcn_mfma_f32_16x16x32_fp8_fp8(a0, qd[g][0], s, 0, 0, 0);
                s = __builtin_amdgcn_mfma_f32_16x16x32_fp8_fp8(a1, qd[g][1], s, 0, 0, 0);
                // lane: S^T[key=ni*16+quad*4+r][q=g*16+l16]
                f32x4 pv;
                for (int r = 0; r < 4; r++) pv[r] = EXP2(s[r]);
                *(unsigned int*)(Pw + (g * 16 + l16) * 128 +
                                 ((ni ^ (l16 & 7)) << 4) + quad * 4) = pk_fp8(pv);
            }
        }

        // ---- O += P * V, l += P * 1 ----
        for (int ks = 0; ks < 4; ks++) {
            const int ub = (ks << 1) + (quad >> 1);
            long vf[4];
            for (int nd = 0; nd < 4; nd++) {
                const int dkl = nd * 16 + l16;
                vf[nd] = *(const long*)(Vt + dkl * 128 + ((ub ^ (dkl & 7)) << 4) + (quad & 1) * 8);
            }
            for (int g = 0; g < 2; g++) {
                long pf = *(const long*)(Pw + (g * 16 + l16) * 128 + ((ub ^ (l16 & 7)) << 4) + (quad & 1) * 8);
                ol[g] = __builtin_amdgcn_mfma_f32_16x16x32_fp8_fp8(pf, ONES8, ol[g], 0, 0, 0);
                for (int nd = 0; nd < 4; nd++)
                    o[g][nd] = __builtin_amdgcn_mfma_f32_16x16x32_fp8_fp8(pf, vf[nd], o[g][nd], 0, 0, 0);
            }
        }
    }

    // l: C rows = q offset quad*4+r, cols identical -> write from l16==0
    if (l16 == 0)
        for (int g = 0; g < 2; g++)
            for (int r = 0; r < 4; r++)
                atomicAdd(&l_tot[(h << 12) + qbase + g * 16 + quad * 4 + r], ol[g][r]);

    for (int g = 0; g < 2; g++)
        for (int nd = 0; nd < 4; nd++)
            for (int r = 0; r < 4; r++) {
                int q = qbase + g * 16 + quad * 4 + r;
                atomicAdd(&vals[hoff + (size_t)q * DK + nd * 16 + l16], o[g][nd][r]);
            }
}

// ----------------- deferred normalize + residual + LayerNorm ---------------
__global__ __launch_bounds__(256) void ln_kernel(
    const float* __restrict__ vals, const float* __restrict__ l_tot,
    const float* __restrict__ x,
    const float* __restrict__ gamma, const float* __restrict__ beta,
    float* __restrict__ out) {
    const int wave = threadIdx.x >> 6, lane = threadIdx.x & 63;
    const int row  = blockIdx.x * 4 + wave;
    const float* v  = vals + (size_t)row * D_MODEL;
    const float* xr = x    + (size_t)row * D_MODEL;

    float t[10];
    float s = 0.f;
    for (int i = 0; i < 10; i++) {
        float linv = 1.0f / l_tot[row * 10 + i];
        t[i] = v[lane + i * 64] * linv + xr[lane + i * 64];
        s += t[i];
    }
    for (int off = 32; off; off >>= 1) s += __shfl_xor(s, off, 64);
    float mean = s * (1.0f / 640.0f);
    float s2 = 0.f;
    for (int i = 0; i < 10; i++) { float d = t[i] - mean; s2 += d * d; }
    for (int off = 32; off; off >>= 1) s2 += __shfl_xor(s2, off, 64);
    float inv = rsqrtf(s2 * (1.0f / 640.0f) + 1e-5f);

    float* orow = out + (size_t)row * D_MODEL;
    for (int i = 0; i < 10; i++) {
        int c = lane + i * 64;
        orow[c] = (t[i] - mean) * inv * gamma[c] + beta[c];
    }
}

// ------------------------------- launcher ----------------------------------
extern "C" void kernel_launch(void* const* d_in, const int* in_sizes, int n_in,
                              void* d_out, int out_size, void* d_ws, size_t ws_size,
                              hipStream_t stream) {
    const float* x     = (const float*)d_in[0];
    const float* Wq    = (const float*)d_in[1];
    const float* Wk    = (const float*)d_in[2];
    const float* Wv    = (const float*)d_in[3];
    const float* gamma = (const float*)d_in[4];
    const float* beta  = (const float*)d_in[5];
    float* out = (float*)d_out;

    char* ws = (char*)d_ws;
    unsigned short* xb  = (unsigned short*)(ws);               // 5,242,880 B
    unsigned char*  Qf8 = (unsigned char*)(ws);                // overlays xb (dead after gemm)
    unsigned short* wqb = (unsigned short*)(ws + 5242880);
    unsigned short* wkb = (unsigned short*)(ws + 6062080);
    unsigned short* wvb = (unsigned short*)(ws + 6881280);
    unsigned short* Qn  = (unsigned short*)(ws + 7700480);     // bf16 Q natural
    unsigned char*  Kp8 = (unsigned char*)(ws + 12943360);     // fp8 K' [h][key][dk]
    unsigned char*  Vp8 = (unsigned char*)(ws + 18186240);     // fp8 V' [h][dk][key]
    unsigned short* Kn  = (unsigned short*)(ws + 23429120);    // aliases vals
    unsigned short* Vn  = (unsigned short*)(ws + 28672000);    //  (exactly)
    float*          vals  = (float*)(ws + 23429120);           // 10,485,760 B
    float*          l_tot = (float*)(ws + 33914880);           //   163,840 B

    cvt_all<<<3800, 256, 0, stream>>>(x, Wq, Wk, Wv, xb, wqb, wkb, wvb,
                                      (f32x4*)l_tot);

    gemm_qkv<<<dim3(5, 32, 3), 256, 0, stream>>>(xb, wqb, wkb, wvb, Qn, Kn, Vn);

    transpose_kv<<<dim3(64, 1, 30), 256, 0, stream>>>(Kn, Kp8, Vn, Vp8, Qn, Qf8);

    attn<<<dim3(320, 3), 256, 0, stream>>>(Qf8, Kp8, Vp8, vals, l_tot);
    ln_kernel<<<1024, 256, 0, stream>>>(vals, l_tot, x, gamma, beta, out);
}

// Round 10
// 162.614 us; speedup vs baseline: 1.2727x; 1.0220x over previous
//
#include <hip/hip_runtime.h>
#if __has_include(<hip/hip_fp8.h>)
#include <hip/hip_fp8.h>
#endif

// ---------------------------------------------------------------------------
// MHABlock: cvt (+l_tot zero, sqrt-softmax-scale folded into Wq AND Wk) ->
// QKV GEMM (bf16, global_load_lds staging) -> fused K/V transpose + fp8
// convert (+Q->fp8, +vals zero) -> split-K(3) fp8 flash attention with
// conflict-engineered LDS layouts:
//   K-tile slot(key,ci) = (key>>3)*32 + ci*8 + (key&7)   [2-way max]
//   V-tile slot(dk,cv)  = (dk>>3)*64 + cv*8 + (dk&7)     [2-way max]
//   P column-major 8B units: addr = pu*256 + q*8          [conflict-free]
// Hardened vs R9: may_alias access types + explicit barrier between the
// P-write (S) phase and P/V-read (PV) phase — closes the warmth-dependent
// ordering race that flipped outputs post-timing in R9.
// -> deferred normalize + residual + LayerNorm.
// ---------------------------------------------------------------------------

typedef __bf16 bf16x8 __attribute__((ext_vector_type(8)));
typedef __bf16 bf16x4 __attribute__((ext_vector_type(4)));
typedef float  f32x4  __attribute__((ext_vector_type(4)));
typedef unsigned short u16x4 __attribute__((ext_vector_type(4)));
typedef unsigned int   u32x4 __attribute__((ext_vector_type(4)));
typedef long           la64  __attribute__((may_alias));
typedef unsigned int   ua32  __attribute__((may_alias));

#define N_TOK   4096
#define D_MODEL 640
#define DK      64
#define HSLAB   (N_TOK * DK)
// sqrt(log2(e)/64): folded into BOTH Wq and Wk -> logits arrive base-2 scaled
#define SQS 0.15014030f

#if __has_builtin(__builtin_amdgcn_exp2f)
#define EXP2(x) __builtin_amdgcn_exp2f(x)
#else
#define EXP2(x) exp2f(x)
#endif

__device__ __forceinline__ void stage16(const void* g, void* lds_uniform) {
    __builtin_amdgcn_global_load_lds(
        (const __attribute__((address_space(1))) unsigned int*)g,
        (__attribute__((address_space(3))) unsigned int*)lds_uniform, 16, 0, 0);
}

__device__ __forceinline__ u16x4 cvt4(f32x4 v) {
    return __builtin_bit_cast(u16x4, __builtin_convertvector(v, bf16x4));
}

// packed f32x4 -> 4x e4m3fn bytes
__device__ __forceinline__ unsigned int pk_fp8(f32x4 v) {
#if __has_builtin(__builtin_amdgcn_cvt_pk_fp8_f32)
    int r = 0;
    r = __builtin_amdgcn_cvt_pk_fp8_f32(v[0], v[1], r, false);
    r = __builtin_amdgcn_cvt_pk_fp8_f32(v[2], v[3], r, true);
    return (unsigned int)r;
#else
    union { unsigned char b[4]; unsigned int u; } x;
    x.b[0] = __hip_fp8_e4m3(v[0]).__x;
    x.b[1] = __hip_fp8_e4m3(v[1]).__x;
    x.b[2] = __hip_fp8_e4m3(v[2]).__x;
    x.b[3] = __hip_fp8_e4m3(v[3]).__x;
    return x.u;
#endif
}

// ---------- fused fp32 -> bf16 (x, Wq*s, Wk*s, Wv) + l_tot zeroing ---------
__global__ __launch_bounds__(256) void cvt_all(const float* __restrict__ x,
                                               const float* __restrict__ w0,
                                               const float* __restrict__ w1,
                                               const float* __restrict__ w2,
                                               unsigned short* __restrict__ xb,
                                               unsigned short* __restrict__ d0,
                                               unsigned short* __restrict__ d1,
                                               unsigned short* __restrict__ d2,
                                               f32x4* __restrict__ ltot4) {
    int i = blockIdx.x * 256 + threadIdx.x;
    if (i >= 962560) { ltot4[i - 962560] = (f32x4){0.f, 0.f, 0.f, 0.f}; return; }
    const float* s; unsigned short* d; int off; float scl = 1.0f;
    if (i < 655360) { s = x; d = xb; off = i; }
    else {
        int j = i - 655360;
        int w = j / 102400; off = j - w * 102400;
        s = (w == 0) ? w0 : (w == 1) ? w1 : w2;
        d = (w == 0) ? d0 : (w == 1) ? d1 : d2;
        if (w < 2) scl = SQS;   // Wq, Wk carry sqrt of softmax scale
    }
    f32x4 v = ((const f32x4*)s)[off];
    v[0] *= scl; v[1] *= scl; v[2] *= scl; v[3] *= scl;
    ((u16x4*)d)[off] = cvt4(v);
}

// ------------------------ QKV NT-GEMM: C = x @ W^T -------------------------
__global__ __launch_bounds__(256, 2) void gemm_qkv(
    const unsigned short* __restrict__ xb,
    const unsigned short* __restrict__ wq,
    const unsigned short* __restrict__ wk,
    const unsigned short* __restrict__ wv,
    unsigned short* __restrict__ Qo,
    unsigned short* __restrict__ Ko,
    unsigned short* __restrict__ Vo) {
    const int mode = blockIdx.z;
    const unsigned short* W = (mode == 0) ? wq : (mode == 1) ? wk : wv;
    unsigned short*       C = (mode == 0) ? Qo : (mode == 1) ? Ko : Vo;
    const int m0 = blockIdx.y * 128;
    const int n0 = blockIdx.x * 128;

    __shared__ unsigned short As[4096];
    __shared__ unsigned short Bs[4096];

    const int tid  = threadIdx.x;
    const int lane = tid & 63;
    const int wave = tid >> 6;
    const int quad = lane >> 4, l16 = lane & 15;
    const int wm = (wave >> 1) * 64, wn = (wave & 1) * 64;
    const int swz3 = l16 & 3;

    f32x4 acc[4][4] = {};

    const int c0 = wave * 64 + lane, c1 = c0 + 256;
    const int r0 = c0 >> 2, u0 = ((c0 & 3) ^ (r0 & 3)) * 8;
    const int r1 = c1 >> 2, u1 = ((c1 & 3) ^ (r1 & 3)) * 8;
    const int lb0 = (wave * 64) * 8, lb1 = lb0 + 2048;

    for (int kt = 0; kt < D_MODEL; kt += 32) {
        __syncthreads();
        stage16(&xb[(size_t)(m0 + r0) * D_MODEL + kt + u0], As + lb0);
        stage16(&xb[(size_t)(m0 + r1) * D_MODEL + kt + u1], As + lb1);
        stage16(&W [(size_t)(n0 + r0) * D_MODEL + kt + u0], Bs + lb0);
        stage16(&W [(size_t)(n0 + r1) * D_MODEL + kt + u1], Bs + lb1);
        __syncthreads();

        bf16x8 af[4], bfr[4];
        for (int mi = 0; mi < 4; mi++)
            af[mi] = *(const bf16x8*)&As[(wm + mi * 16 + l16) * 32 + (quad ^ swz3) * 8];
        for (int ni = 0; ni < 4; ni++)
            bfr[ni] = *(const bf16x8*)&Bs[(wn + ni * 16 + l16) * 32 + (quad ^ swz3) * 8];
        for (int mi = 0; mi < 4; mi++)
            for (int ni = 0; ni < 4; ni++)
                acc[mi][ni] = __builtin_amdgcn_mfma_f32_16x16x32_bf16(af[mi], bfr[ni], acc[mi][ni], 0, 0, 0);
    }

    for (int mi = 0; mi < 4; mi++)
        for (int ni = 0; ni < 4; ni++) {
            u16x4 cv = cvt4(acc[mi][ni]);
            for (int r = 0; r < 4; r++) {
                int row = m0 + wm + mi * 16 + quad * 4 + r;
                int col = n0 + wn + ni * 16 + l16;
                C[(size_t)row * D_MODEL + col] = cv[r];
            }
        }
}

// ------ fused per-head transpose -> fp8 (K',V') + Q->fp8 + vals zero -------
__global__ __launch_bounds__(256) void transpose_kv(
    const unsigned short* __restrict__ Kn, unsigned char* __restrict__ Kp8,
    const unsigned short* __restrict__ Vn, unsigned char* __restrict__ Vp8,
    const unsigned short* __restrict__ Qn, unsigned char* __restrict__ Qf8) {
    const int z = blockIdx.z;
    const int t = threadIdx.x;

    if (z >= 20) {   // Q convert: head slab, flat
        const size_t base = (size_t)(z - 20) * HSLAB + blockIdx.x * 4096 + t * 16;
        bf16x8 v0 = *(const bf16x8*)&Qn[base];
        bf16x8 v1 = *(const bf16x8*)&Qn[base + 8];
        f32x4 a = {(float)v0[0], (float)v0[1], (float)v0[2], (float)v0[3]};
        f32x4 b = {(float)v0[4], (float)v0[5], (float)v0[6], (float)v0[7]};
        f32x4 c = {(float)v1[0], (float)v1[1], (float)v1[2], (float)v1[3]};
        f32x4 d = {(float)v1[4], (float)v1[5], (float)v1[6], (float)v1[7]};
        u32x4 o = {pk_fp8(a), pk_fp8(b), pk_fp8(c), pk_fp8(d)};
        *(u32x4*)&Qf8[base] = o;
        return;
    }

    __shared__ unsigned short T[64][66];
    const unsigned short* src; unsigned char* dst;
    int R, Cc, r0, c0;
    if (z < 10) { src = Kn; dst = Kp8; R = 64;   Cc = 4096; r0 = 0; c0 = blockIdx.x * 64; }
    else        { src = Vn; dst = Vp8; R = 4096; Cc = 64;   r0 = blockIdx.x * 64; c0 = 0; }
    const size_t hb = (size_t)(z % 10) * HSLAB;
    const int rr = t >> 3, c8 = (t & 7) * 8;

    for (int hf = 0; hf < 2; hf++) {
        int r = rr + hf * 32;
        bf16x8 v = *(const bf16x8*)&src[hb + (size_t)(r0 + r) * Cc + c0 + c8];
        for (int j = 0; j < 8; j++) T[r][c8 + j] = ((unsigned short*)&v)[j];
    }
    __syncthreads();
    // zero the consumed source tile (Kn+Vn exactly cover the fp32 vals buf)
    const bf16x8 zz = {};
    for (int hf = 0; hf < 2; hf++) {
        int r = rr + hf * 32;
        *(bf16x8*)&((unsigned short*)src)[hb + (size_t)(r0 + r) * Cc + c0 + c8] = zz;
    }
    for (int hf = 0; hf < 2; hf++) {
        int oc = rr + hf * 32;
        f32x4 lo, hi;
        for (int j = 0; j < 4; j++) {
            lo[j] = __builtin_bit_cast(float, (unsigned int)T[c8 + j][oc] << 16);
            hi[j] = __builtin_bit_cast(float, (unsigned int)T[c8 + 4 + j][oc] << 16);
        }
        uint2 ov; ov.x = pk_fp8(lo); ov.y = pk_fp8(hi);
        size_t dcol = (z < 10) ? ((size_t)(c0 + oc) * 64 + r0 + c8)
                               : ((size_t)oc * 4096 + r0 + c8);
        *(uint2*)&dst[hb + dcol] = ov;
    }
}

// ------------------------------- attention (fp8) ---------------------------
// grid (320, 3): x = head*32 + qtile(128 rows), y = kpart (11/11/10 tiles
// of 128 keys). 4 waves x 32 q. Conflict-engineered LDS layouts (see top).
__global__ __launch_bounds__(256, 4) void attn(
    const unsigned char* __restrict__ Qf8,   // [h][q][dk] fp8
    const unsigned char* __restrict__ Kp8,   // [h][key][dk] fp8
    const unsigned char* __restrict__ Vp8,   // [h][dk][key] fp8
    float* __restrict__ vals,                // pre-zeroed (transpose_kv)
    float* __restrict__ l_tot) {             // pre-zeroed (cvt_all)
    const int h  = blockIdx.x >> 5;
    const int qt = blockIdx.x & 31;
    const int ntile = (blockIdx.y == 2) ? 10 : 11;
    const int tile0 = blockIdx.y * 11;
    const int lane = threadIdx.x & 63;
    const int wave = threadIdx.x >> 6;
    const int quad = lane >> 4, l16 = lane & 15;
    const size_t hoff = (size_t)h * HSLAB;

    __shared__ unsigned char sm[32768];
    unsigned char* Kt = sm;                        // 8KB: slot(key,ci)
    unsigned char* Vt = sm + 8192;                 // 8KB: slot(dk,cv)
    unsigned char* Pw = sm + 16384 + wave * 4096;  // 4KB: col-major 8B units

    const int qbase = qt * 128 + wave * 32;
    long qd[2][2];
    for (int g = 0; g < 2; g++) {
        const unsigned char* qp = Qf8 + hoff + (size_t)(qbase + g * 16 + l16) * 64 + quad * 8;
        qd[g][0] = *(const la64*)(qp);
        qd[g][1] = *(const la64*)(qp + 32);
    }

    f32x4 o[2][4] = {};
    f32x4 ol[2] = {};
    const long ONES8 = 0x3838383838383838L;   // e4m3 1.0 x8

    // staging: LDS chunk c holds: K (key=(c>>5)*8+(c&7), ci=(c>>3)&3)
    //                             V (dk =(c>>6)*8+(c&7), cv=(c>>3)&7)
    const int cA = wave * 64 + lane, cB = cA + 256;
    const int kKeyA = ((cA >> 5) << 3) + (cA & 7), kCiA = (cA >> 3) & 3;
    const int kKeyB = ((cB >> 5) << 3) + (cB & 7), kCiB = (cB >> 3) & 3;
    const int vDkA  = ((cA >> 6) << 3) + (cA & 7), vCvA = (cA >> 3) & 7;
    const int vDkB  = ((cB >> 6) << 3) + (cB & 7), vCvB = (cB >> 3) & 7;

    // fragment-read bases
    const int kfb = (l16 >> 3) * 512 + (quad >> 1) * 128 + (l16 & 7) * 16 + (quad & 1) * 8;
    const int vfb = (l16 >> 3) * 1024 + (quad >> 1) * 128 + (l16 & 7) * 16 + (quad & 1) * 8;

    for (int t = 0; t < ntile; t++) {
        const int keyb = (tile0 + t) << 7;
        __syncthreads();
        stage16(Kp8 + hoff + (size_t)(keyb + kKeyA) * 64 + kCiA * 16, Kt + wave * 1024);
        stage16(Kp8 + hoff + (size_t)(keyb + kKeyB) * 64 + kCiB * 16, Kt + 4096 + wave * 1024);
        stage16(Vp8 + hoff + (size_t)vDkA * N_TOK + keyb + vCvA * 16, Vt + wave * 1024);
        stage16(Vp8 + hoff + (size_t)vDkB * N_TOK + keyb + vCvB * 16, Vt + 4096 + wave * 1024);
        __syncthreads();

        // ---- S^T: A = K rows (key), B = Q (pre-scaled); exp2 -> P fp8 ----
        for (int ni = 0; ni < 8; ni++) {
            // slot(key=ni*16+l16, ci=(quad>>1)+2s): a0 s=0, a1 s=1 (+256B)
            const unsigned char* kp = Kt + ni * 1024 + kfb;
            long a0 = *(const la64*)(kp);
            long a1 = *(const la64*)(kp + 256);
            for (int g = 0; g < 2; g++) {
                f32x4 s = {};
                s = __builtin_amdgcn_mfma_f32_16x16x32_fp8_fp8(a0, qd[g][0], s, 0, 0, 0);
                s = __builtin_amdgcn_mfma_f32_16x16x32_fp8_fp8(a1, qd[g][1], s, 0, 0, 0);
                // lane: S^T[key=ni*16+quad*4+r][q=g*16+l16]
                f32x4 pv;
                for (int r = 0; r < 4; r++) pv[r] = EXP2(s[r]);
                // P col-major: pu = ni*2+(quad>>1), q = g*16+l16, u32 sel quad&1
                *(ua32*)(Pw + (ni * 2 + (quad >> 1)) * 256 +
                         (g * 16 + l16) * 8 + (quad & 1) * 4) = pk_fp8(pv);
            }
        }

        // Ordering edge: all P writes (cross-lane producers) must land before
        // any PV-phase read. Full barrier drains lgkmcnt/vmcnt for all waves.
        __syncthreads();

        // ---- O += P * V, l += P * 1 ----
        for (int ks = 0; ks < 4; ks++) {
            long vf[4];
            for (int nd = 0; nd < 4; nd++)
                vf[nd] = *(const la64*)(Vt + nd * 2048 + ks * 256 + vfb);
            for (int g = 0; g < 2; g++) {
                long pf = *(const la64*)(Pw + (ks * 4 + quad) * 256 + (g * 16 + l16) * 8);
                ol[g] = __builtin_amdgcn_mfma_f32_16x16x32_fp8_fp8(pf, ONES8, ol[g], 0, 0, 0);
                for (int nd = 0; nd < 4; nd++)
                    o[g][nd] = __builtin_amdgcn_mfma_f32_16x16x32_fp8_fp8(pf, vf[nd], o[g][nd], 0, 0, 0);
            }
        }
    }

    // l: C rows = q offset quad*4+r, cols identical -> write from l16==0
    if (l16 == 0)
        for (int g = 0; g < 2; g++)
            for (int r = 0; r < 4; r++)
                atomicAdd(&l_tot[(h << 12) + qbase + g * 16 + quad * 4 + r], ol[g][r]);

    for (int g = 0; g < 2; g++)
        for (int nd = 0; nd < 4; nd++)
            for (int r = 0; r < 4; r++) {
                int q = qbase + g * 16 + quad * 4 + r;
                atomicAdd(&vals[hoff + (size_t)q * DK + nd * 16 + l16], o[g][nd][r]);
            }
}

// ----------------- deferred normalize + residual + LayerNorm ---------------
__global__ __launch_bounds__(256) void ln_kernel(
    const float* __restrict__ vals, const float* __restrict__ l_tot,
    const float* __restrict__ x,
    const float* __restrict__ gamma, const float* __restrict__ beta,
    float* __restrict__ out) {
    const int wave = threadIdx.x >> 6, lane = threadIdx.x & 63;
    const int row  = blockIdx.x * 4 + wave;
    const float* v  = vals + (size_t)row * D_MODEL;
    const float* xr = x    + (size_t)row * D_MODEL;

    float t[10];
    float s = 0.f;
    for (int i = 0; i < 10; i++) {
        float linv = 1.0f / l_tot[row * 10 + i];
        t[i] = v[lane + i * 64] * linv + xr[lane + i * 64];
        s += t[i];
    }
    for (int off = 32; off; off >>= 1) s += __shfl_xor(s, off, 64);
    float mean = s * (1.0f / 640.0f);
    float s2 = 0.f;
    for (int i = 0; i < 10; i++) { float d = t[i] - mean; s2 += d * d; }
    for (int off = 32; off; off >>= 1) s2 += __shfl_xor(s2, off, 64);
    float inv = rsqrtf(s2 * (1.0f / 640.0f) + 1e-5f);

    float* orow = out + (size_t)row * D_MODEL;
    for (int i = 0; i < 10; i++) {
        int c = lane + i * 64;
        orow[c] = (t[i] - mean) * inv * gamma[c] + beta[c];
    }
}

// ------------------------------- launcher ----------------------------------
extern "C" void kernel_launch(void* const* d_in, const int* in_sizes, int n_in,
                              void* d_out, int out_size, void* d_ws, size_t ws_size,
                              hipStream_t stream) {
    const float* x     = (const float*)d_in[0];
    const float* Wq    = (const float*)d_in[1];
    const float* Wk    = (const float*)d_in[2];
    const float* Wv    = (const float*)d_in[3];
    const float* gamma = (const float*)d_in[4];
    const float* beta  = (const float*)d_in[5];
    float* out = (float*)d_out;

    char* ws = (char*)d_ws;
    unsigned short* xb  = (unsigned short*)(ws);               // 5,242,880 B
    unsigned char*  Qf8 = (unsigned char*)(ws);                // overlays xb (dead after gemm)
    unsigned short* wqb = (unsigned short*)(ws + 5242880);
    unsigned short* wkb = (unsigned short*)(ws + 6062080);
    unsigned short* wvb = (unsigned short*)(ws + 6881280);
    unsigned short* Qn  = (unsigned short*)(ws + 7700480);     // bf16 Q natural
    unsigned char*  Kp8 = (unsigned char*)(ws + 12943360);     // fp8 K' [h][key][dk]
    unsigned char*  Vp8 = (unsigned char*)(ws + 18186240);     // fp8 V' [h][dk][key]
    unsigned short* Kn  = (unsigned short*)(ws + 23429120);    // aliases vals
    unsigned short* Vn  = (unsigned short*)(ws + 28672000);    //  (exactly)
    float*          vals  = (float*)(ws + 23429120);           // 10,485,760 B
    float*          l_tot = (float*)(ws + 33914880);           //   163,840 B

    cvt_all<<<3800, 256, 0, stream>>>(x, Wq, Wk, Wv, xb, wqb, wkb, wvb,
                                      (f32x4*)l_tot);

    gemm_qkv<<<dim3(5, 32, 3), 256, 0, stream>>>(xb, wqb, wkb, wvb, Qn, Kn, Vn);

    transpose_kv<<<dim3(64, 1, 30), 256, 0, stream>>>(Kn, Kp8, Vn, Vp8, Qn, Qf8);

    attn<<<dim3(320, 3), 256, 0, stream>>>(Qf8, Kp8, Vp8, vals, l_tot);
    ln_kernel<<<1024, 256, 0, stream>>>(vals, l_tot, x, gamma, beta, out);
}

// Round 11
// 160.185 us; speedup vs baseline: 1.2920x; 1.0152x over previous
//
#include <hip/hip_runtime.h>
#if __has_include(<hip/hip_fp8.h>)
#include <hip/hip_fp8.h>
#endif

// ---------------------------------------------------------------------------
// MHABlock: cvt (+l_tot zero, sqrt-softmax-scale folded into Wq AND Wk) ->
// QKV GEMM (bf16, BK=64, global_load_lds, conflict-free chunk layout) ->
// fused K/V transpose + fp8 convert (+Q->fp8, +vals zero) -> split-K(3) fp8
// flash attention (conflict-engineered LDS layouts, ordering-hardened) ->
// deferred normalize + residual + LayerNorm.
// ---------------------------------------------------------------------------

typedef __bf16 bf16x8 __attribute__((ext_vector_type(8)));
typedef __bf16 bf16x4 __attribute__((ext_vector_type(4)));
typedef float  f32x4  __attribute__((ext_vector_type(4)));
typedef unsigned short u16x4 __attribute__((ext_vector_type(4)));
typedef unsigned int   u32x4 __attribute__((ext_vector_type(4)));
typedef long           la64  __attribute__((may_alias));
typedef unsigned int   ua32  __attribute__((may_alias));

#define N_TOK   4096
#define D_MODEL 640
#define DK      64
#define HSLAB   (N_TOK * DK)
// sqrt(log2(e)/64): folded into BOTH Wq and Wk -> logits arrive base-2 scaled
#define SQS 0.15014030f

#if __has_builtin(__builtin_amdgcn_exp2f)
#define EXP2(x) __builtin_amdgcn_exp2f(x)
#else
#define EXP2(x) exp2f(x)
#endif

__device__ __forceinline__ void stage16(const void* g, void* lds_uniform) {
    __builtin_amdgcn_global_load_lds(
        (const __attribute__((address_space(1))) unsigned int*)g,
        (__attribute__((address_space(3))) unsigned int*)lds_uniform, 16, 0, 0);
}

__device__ __forceinline__ u16x4 cvt4(f32x4 v) {
    return __builtin_bit_cast(u16x4, __builtin_convertvector(v, bf16x4));
}

// packed f32x4 -> 4x e4m3fn bytes
__device__ __forceinline__ unsigned int pk_fp8(f32x4 v) {
#if __has_builtin(__builtin_amdgcn_cvt_pk_fp8_f32)
    int r = 0;
    r = __builtin_amdgcn_cvt_pk_fp8_f32(v[0], v[1], r, false);
    r = __builtin_amdgcn_cvt_pk_fp8_f32(v[2], v[3], r, true);
    return (unsigned int)r;
#else
    union { unsigned char b[4]; unsigned int u; } x;
    x.b[0] = __hip_fp8_e4m3(v[0]).__x;
    x.b[1] = __hip_fp8_e4m3(v[1]).__x;
    x.b[2] = __hip_fp8_e4m3(v[2]).__x;
    x.b[3] = __hip_fp8_e4m3(v[3]).__x;
    return x.u;
#endif
}

// ---------- fused fp32 -> bf16 (x, Wq*s, Wk*s, Wv) + l_tot zeroing ---------
__global__ __launch_bounds__(256) void cvt_all(const float* __restrict__ x,
                                               const float* __restrict__ w0,
                                               const float* __restrict__ w1,
                                               const float* __restrict__ w2,
                                               unsigned short* __restrict__ xb,
                                               unsigned short* __restrict__ d0,
                                               unsigned short* __restrict__ d1,
                                               unsigned short* __restrict__ d2,
                                               f32x4* __restrict__ ltot4) {
    int i = blockIdx.x * 256 + threadIdx.x;
    if (i >= 962560) { ltot4[i - 962560] = (f32x4){0.f, 0.f, 0.f, 0.f}; return; }
    const float* s; unsigned short* d; int off; float scl = 1.0f;
    if (i < 655360) { s = x; d = xb; off = i; }
    else {
        int j = i - 655360;
        int w = j / 102400; off = j - w * 102400;
        s = (w == 0) ? w0 : (w == 1) ? w1 : w2;
        d = (w == 0) ? d0 : (w == 1) ? d1 : d2;
        if (w < 2) scl = SQS;   // Wq, Wk carry sqrt of softmax scale
    }
    f32x4 v = ((const f32x4*)s)[off];
    v[0] *= scl; v[1] *= scl; v[2] *= scl; v[3] *= scl;
    ((u16x4*)d)[off] = cvt4(v);
}

// ------------------------ QKV NT-GEMM: C = x @ W^T -------------------------
// M=4096, N=640, K=640. 128x128 tile, BK=64, 4 waves each 64x64.
// LDS physical chunk p (16B) holds (row=p>>3, unit=(p&7)^(row&7)):
// staging = coalesced 128B global segments; fragment b128 reads conflict-free
// (8-lane phase covers banks 0..31 exactly once). 10 K-iters -> half the
// barrier drains of the BK=32 version.
__global__ __launch_bounds__(256, 2) void gemm_qkv(
    const unsigned short* __restrict__ xb,
    const unsigned short* __restrict__ wq,
    const unsigned short* __restrict__ wk,
    const unsigned short* __restrict__ wv,
    unsigned short* __restrict__ Qo,
    unsigned short* __restrict__ Ko,
    unsigned short* __restrict__ Vo) {
    const int mode = blockIdx.z;
    const unsigned short* W = (mode == 0) ? wq : (mode == 1) ? wk : wv;
    unsigned short*       C = (mode == 0) ? Qo : (mode == 1) ? Ko : Vo;
    const int m0 = blockIdx.y * 128;
    const int n0 = blockIdx.x * 128;

    __shared__ unsigned short As[8192];   // 128 rows x 64
    __shared__ unsigned short Bs[8192];

    const int tid  = threadIdx.x;
    const int lane = tid & 63;
    const int wave = tid >> 6;
    const int quad = lane >> 4, l16 = lane & 15;
    const int wm = (wave >> 1) * 64, wn = (wave & 1) * 64;
    const int swz = l16 & 7;

    f32x4 acc[4][4] = {};

    // staging geometry: 4 chunk-groups of 256 per buffer
    int prow[4], pcol[4], lbase[4];
    for (int j = 0; j < 4; j++) {
        int p = j * 256 + tid;
        prow[j] = p >> 3;
        pcol[j] = ((p & 7) ^ (prow[j] & 7)) * 8;
        lbase[j] = (j * 256 + wave * 64) * 8;   // element offset of wave's run
    }

    for (int kt = 0; kt < D_MODEL; kt += 64) {
        __syncthreads();
        for (int j = 0; j < 4; j++) {
            stage16(&xb[(size_t)(m0 + prow[j]) * D_MODEL + kt + pcol[j]], As + lbase[j]);
            stage16(&W [(size_t)(n0 + prow[j]) * D_MODEL + kt + pcol[j]], Bs + lbase[j]);
        }
        __syncthreads();

        for (int s = 0; s < 2; s++) {
            bf16x8 af[4], bfr[4];
            for (int mi = 0; mi < 4; mi++) {
                int row = wm + mi * 16 + l16;
                af[mi] = *(const bf16x8*)&As[row * 64 + (((s << 2) + quad) ^ swz) * 8];
            }
            for (int ni = 0; ni < 4; ni++) {
                int row = wn + ni * 16 + l16;
                bfr[ni] = *(const bf16x8*)&Bs[row * 64 + (((s << 2) + quad) ^ swz) * 8];
            }
            for (int mi = 0; mi < 4; mi++)
                for (int ni = 0; ni < 4; ni++)
                    acc[mi][ni] = __builtin_amdgcn_mfma_f32_16x16x32_bf16(af[mi], bfr[ni], acc[mi][ni], 0, 0, 0);
        }
    }

    for (int mi = 0; mi < 4; mi++)
        for (int ni = 0; ni < 4; ni++) {
            u16x4 cv = cvt4(acc[mi][ni]);
            for (int r = 0; r < 4; r++) {
                int row = m0 + wm + mi * 16 + quad * 4 + r;
                int col = n0 + wn + ni * 16 + l16;
                C[(size_t)row * D_MODEL + col] = cv[r];
            }
        }
}

// ------ fused per-head transpose -> fp8 (K',V') + Q->fp8 + vals zero -------
__global__ __launch_bounds__(256) void transpose_kv(
    const unsigned short* __restrict__ Kn, unsigned char* __restrict__ Kp8,
    const unsigned short* __restrict__ Vn, unsigned char* __restrict__ Vp8,
    const unsigned short* __restrict__ Qn, unsigned char* __restrict__ Qf8) {
    const int z = blockIdx.z;
    const int t = threadIdx.x;

    if (z >= 20) {   // Q convert: head slab, flat
        const size_t base = (size_t)(z - 20) * HSLAB + blockIdx.x * 4096 + t * 16;
        bf16x8 v0 = *(const bf16x8*)&Qn[base];
        bf16x8 v1 = *(const bf16x8*)&Qn[base + 8];
        f32x4 a = {(float)v0[0], (float)v0[1], (float)v0[2], (float)v0[3]};
        f32x4 b = {(float)v0[4], (float)v0[5], (float)v0[6], (float)v0[7]};
        f32x4 c = {(float)v1[0], (float)v1[1], (float)v1[2], (float)v1[3]};
        f32x4 d = {(float)v1[4], (float)v1[5], (float)v1[6], (float)v1[7]};
        u32x4 o = {pk_fp8(a), pk_fp8(b), pk_fp8(c), pk_fp8(d)};
        *(u32x4*)&Qf8[base] = o;
        return;
    }

    __shared__ unsigned short T[64][66];
    const unsigned short* src; unsigned char* dst;
    int R, Cc, r0, c0;
    if (z < 10) { src = Kn; dst = Kp8; R = 64;   Cc = 4096; r0 = 0; c0 = blockIdx.x * 64; }
    else        { src = Vn; dst = Vp8; R = 4096; Cc = 64;   r0 = blockIdx.x * 64; c0 = 0; }
    const size_t hb = (size_t)(z % 10) * HSLAB;
    const int rr = t >> 3, c8 = (t & 7) * 8;

    for (int hf = 0; hf < 2; hf++) {
        int r = rr + hf * 32;
        bf16x8 v = *(const bf16x8*)&src[hb + (size_t)(r0 + r) * Cc + c0 + c8];
        for (int j = 0; j < 8; j++) T[r][c8 + j] = ((unsigned short*)&v)[j];
    }
    __syncthreads();
    // zero the consumed source tile (Kn+Vn exactly cover the fp32 vals buf)
    const bf16x8 zz = {};
    for (int hf = 0; hf < 2; hf++) {
        int r = rr + hf * 32;
        *(bf16x8*)&((unsigned short*)src)[hb + (size_t)(r0 + r) * Cc + c0 + c8] = zz;
    }
    for (int hf = 0; hf < 2; hf++) {
        int oc = rr + hf * 32;
        f32x4 lo, hi;
        for (int j = 0; j < 4; j++) {
            lo[j] = __builtin_bit_cast(float, (unsigned int)T[c8 + j][oc] << 16);
            hi[j] = __builtin_bit_cast(float, (unsigned int)T[c8 + 4 + j][oc] << 16);
        }
        uint2 ov; ov.x = pk_fp8(lo); ov.y = pk_fp8(hi);
        size_t dcol = (z < 10) ? ((size_t)(c0 + oc) * 64 + r0 + c8)
                               : ((size_t)oc * 4096 + r0 + c8);
        *(uint2*)&dst[hb + dcol] = ov;
    }
}

// ------------------------------- attention (fp8) ---------------------------
// grid (320, 3): x = head*32 + qtile(128 rows), y = kpart (11/11/10 tiles
// of 128 keys). 4 waves x 32 q. Conflict-engineered LDS layouts.
__global__ __launch_bounds__(256, 4) void attn(
    const unsigned char* __restrict__ Qf8,   // [h][q][dk] fp8
    const unsigned char* __restrict__ Kp8,   // [h][key][dk] fp8
    const unsigned char* __restrict__ Vp8,   // [h][dk][key] fp8
    float* __restrict__ vals,                // pre-zeroed (transpose_kv)
    float* __restrict__ l_tot) {             // pre-zeroed (cvt_all)
    const int h  = blockIdx.x >> 5;
    const int qt = blockIdx.x & 31;
    const int ntile = (blockIdx.y == 2) ? 10 : 11;
    const int tile0 = blockIdx.y * 11;
    const int lane = threadIdx.x & 63;
    const int wave = threadIdx.x >> 6;
    const int quad = lane >> 4, l16 = lane & 15;
    const size_t hoff = (size_t)h * HSLAB;

    __shared__ unsigned char sm[32768];
    unsigned char* Kt = sm;                        // 8KB: slot(key,ci)
    unsigned char* Vt = sm + 8192;                 // 8KB: slot(dk,cv)
    unsigned char* Pw = sm + 16384 + wave * 4096;  // 4KB: col-major 8B units

    const int qbase = qt * 128 + wave * 32;
    long qd[2][2];
    for (int g = 0; g < 2; g++) {
        const unsigned char* qp = Qf8 + hoff + (size_t)(qbase + g * 16 + l16) * 64 + quad * 8;
        qd[g][0] = *(const la64*)(qp);
        qd[g][1] = *(const la64*)(qp + 32);
    }

    f32x4 o[2][4] = {};
    f32x4 ol[2] = {};
    const long ONES8 = 0x3838383838383838L;   // e4m3 1.0 x8

    // staging: LDS chunk c holds: K (key=(c>>5)*8+(c&7), ci=(c>>3)&3)
    //                             V (dk =(c>>6)*8+(c&7), cv=(c>>3)&7)
    const int cA = wave * 64 + lane, cB = cA + 256;
    const int kKeyA = ((cA >> 5) << 3) + (cA & 7), kCiA = (cA >> 3) & 3;
    const int kKeyB = ((cB >> 5) << 3) + (cB & 7), kCiB = (cB >> 3) & 3;
    const int vDkA  = ((cA >> 6) << 3) + (cA & 7), vCvA = (cA >> 3) & 7;
    const int vDkB  = ((cB >> 6) << 3) + (cB & 7), vCvB = (cB >> 3) & 7;

    // fragment-read bases
    const int kfb = (l16 >> 3) * 512 + (quad >> 1) * 128 + (l16 & 7) * 16 + (quad & 1) * 8;
    const int vfb = (l16 >> 3) * 1024 + (quad >> 1) * 128 + (l16 & 7) * 16 + (quad & 1) * 8;

    for (int t = 0; t < ntile; t++) {
        const int keyb = (tile0 + t) << 7;
        __syncthreads();
        stage16(Kp8 + hoff + (size_t)(keyb + kKeyA) * 64 + kCiA * 16, Kt + wave * 1024);
        stage16(Kp8 + hoff + (size_t)(keyb + kKeyB) * 64 + kCiB * 16, Kt + 4096 + wave * 1024);
        stage16(Vp8 + hoff + (size_t)vDkA * N_TOK + keyb + vCvA * 16, Vt + wave * 1024);
        stage16(Vp8 + hoff + (size_t)vDkB * N_TOK + keyb + vCvB * 16, Vt + 4096 + wave * 1024);
        __syncthreads();

        // ---- S^T: A = K rows (key), B = Q (pre-scaled); exp2 -> P fp8 ----
        for (int ni = 0; ni < 8; ni++) {
            const unsigned char* kp = Kt + ni * 1024 + kfb;
            long a0 = *(const la64*)(kp);
            long a1 = *(const la64*)(kp + 256);
            for (int g = 0; g < 2; g++) {
                f32x4 s = {};
                s = __builtin_amdgcn_mfma_f32_16x16x32_fp8_fp8(a0, qd[g][0], s, 0, 0, 0);
                s = __builtin_amdgcn_mfma_f32_16x16x32_fp8_fp8(a1, qd[g][1], s, 0, 0, 0);
                f32x4 pv;
                for (int r = 0; r < 4; r++) pv[r] = EXP2(s[r]);
                *(ua32*)(Pw + (ni * 2 + (quad >> 1)) * 256 +
                         (g * 16 + l16) * 8 + (quad & 1) * 4) = pk_fp8(pv);
            }
        }

        // Ordering edge: all P writes must land before any PV-phase read.
        __syncthreads();

        // ---- O += P * V, l += P * 1 ----
        for (int ks = 0; ks < 4; ks++) {
            long vf[4];
            for (int nd = 0; nd < 4; nd++)
                vf[nd] = *(const la64*)(Vt + nd * 2048 + ks * 256 + vfb);
            for (int g = 0; g < 2; g++) {
                long pf = *(const la64*)(Pw + (ks * 4 + quad) * 256 + (g * 16 + l16) * 8);
                ol[g] = __builtin_amdgcn_mfma_f32_16x16x32_fp8_fp8(pf, ONES8, ol[g], 0, 0, 0);
                for (int nd = 0; nd < 4; nd++)
                    o[g][nd] = __builtin_amdgcn_mfma_f32_16x16x32_fp8_fp8(pf, vf[nd], o[g][nd], 0, 0, 0);
            }
        }
    }

    // l: C rows = q offset quad*4+r, cols identical -> write from l16==0
    if (l16 == 0)
        for (int g = 0; g < 2; g++)
            for (int r = 0; r < 4; r++)
                atomicAdd(&l_tot[(h << 12) + qbase + g * 16 + quad * 4 + r], ol[g][r]);

    for (int g = 0; g < 2; g++)
        for (int nd = 0; nd < 4; nd++)
            for (int r = 0; r < 4; r++) {
                int q = qbase + g * 16 + quad * 4 + r;
                atomicAdd(&vals[hoff + (size_t)q * DK + nd * 16 + l16], o[g][nd][r]);
            }
}

// ----------------- deferred normalize + residual + LayerNorm ---------------
__global__ __launch_bounds__(256) void ln_kernel(
    const float* __restrict__ vals, const float* __restrict__ l_tot,
    const float* __restrict__ x,
    const float* __restrict__ gamma, const float* __restrict__ beta,
    float* __restrict__ out) {
    const int wave = threadIdx.x >> 6, lane = threadIdx.x & 63;
    const int row  = blockIdx.x * 4 + wave;
    const float* v  = vals + (size_t)row * D_MODEL;
    const float* xr = x    + (size_t)row * D_MODEL;

    float t[10];
    float s = 0.f;
    for (int i = 0; i < 10; i++) {
        float linv = 1.0f / l_tot[row * 10 + i];
        t[i] = v[lane + i * 64] * linv + xr[lane + i * 64];
        s += t[i];
    }
    for (int off = 32; off; off >>= 1) s += __shfl_xor(s, off, 64);
    float mean = s * (1.0f / 640.0f);
    float s2 = 0.f;
    for (int i = 0; i < 10; i++) { float d = t[i] - mean; s2 += d * d; }
    for (int off = 32; off; off >>= 1) s2 += __shfl_xor(s2, off, 64);
    float inv = rsqrtf(s2 * (1.0f / 640.0f) + 1e-5f);

    float* orow = out + (size_t)row * D_MODEL;
    for (int i = 0; i < 10; i++) {
        int c = lane + i * 64;
        orow[c] = (t[i] - mean) * inv * gamma[c] + beta[c];
    }
}

// ------------------------------- launcher ----------------------------------
extern "C" void kernel_launch(void* const* d_in, const int* in_sizes, int n_in,
                              void* d_out, int out_size, void* d_ws, size_t ws_size,
                              hipStream_t stream) {
    const float* x     = (const float*)d_in[0];
    const float* Wq    = (const float*)d_in[1];
    const float* Wk    = (const float*)d_in[2];
    const float* Wv    = (const float*)d_in[3];
    const float* gamma = (const float*)d_in[4];
    const float* beta  = (const float*)d_in[5];
    float* out = (float*)d_out;

    char* ws = (char*)d_ws;
    unsigned short* xb  = (unsigned short*)(ws);               // 5,242,880 B
    unsigned char*  Qf8 = (unsigned char*)(ws);                // overlays xb (dead after gemm)
    unsigned short* wqb = (unsigned short*)(ws + 5242880);
    unsigned short* wkb = (unsigned short*)(ws + 6062080);
    unsigned short* wvb = (unsigned short*)(ws + 6881280);
    unsigned short* Qn  = (unsigned short*)(ws + 7700480);     // bf16 Q natural
    unsigned char*  Kp8 = (unsigned char*)(ws + 12943360);     // fp8 K' [h][key][dk]
    unsigned char*  Vp8 = (unsigned char*)(ws + 18186240);     // fp8 V' [h][dk][key]
    unsigned short* Kn  = (unsigned short*)(ws + 23429120);    // aliases vals
    unsigned short* Vn  = (unsigned short*)(ws + 28672000);    //  (exactly)
    float*          vals  = (float*)(ws + 23429120);           // 10,485,760 B
    float*          l_tot = (float*)(ws + 33914880);           //   163,840 B

    cvt_all<<<3800, 256, 0, stream>>>(x, Wq, Wk, Wv, xb, wqb, wkb, wvb,
                                      (f32x4*)l_tot);

    gemm_qkv<<<dim3(5, 32, 3), 256, 0, stream>>>(xb, wqb, wkb, wvb, Qn, Kn, Vn);

    transpose_kv<<<dim3(64, 1, 30), 256, 0, stream>>>(Kn, Kp8, Vn, Vp8, Qn, Qf8);

    attn<<<dim3(320, 3), 256, 0, stream>>>(Qf8, Kp8, Vp8, vals, l_tot);
    ln_kernel<<<1024, 256, 0, stream>>>(vals, l_tot, x, gamma, beta, out);
}